// Round 8
// baseline (62.352 us; speedup 1.0000x reference)
//
#include <hip/hip_runtime.h>

#define DEV __device__ __forceinline__

// One wave (64 lanes) simulates TWO samples' 1024-amplitude states.
// flat idx = lane*16 + j ; wire w <-> flat bit (9-w):
//   wires 0..5 -> lane bits 5..0 (masks 32,16,8,4,2,1)
//   wires 6..9 -> local bits 3..0 (masks 8,4,2,1 within j)
//
// Cross-lane partner exchange x[lane^M] (all HW-verified in R7 kernel):
//   mask 32 : __shfl_xor(v,32)
//   mask 16 : ds_swizzle 0x401F          (xor16 bit-mode)
//   mask 8  : DPP row_ror:8   (0x128)
//   mask 4  : ds_swizzle 0x101F          (xor4 bit-mode)
//   mask 2  : DPP quad_perm [2,3,0,1] (0x4E)
//   mask 1  : DPP quad_perm [1,0,3,2] (0xB1)
// CNOT(ctrl=lane bit1, tgt=bit0) : DPP quad_perm [0,1,3,2] (0xB4) — one op.

DEV float shx(float v, int m) { return __shfl_xor(v, m, 64); }

template <int CTRL>
DEV float dppx(float x) {
  int xi = __builtin_bit_cast(int, x);
  return __builtin_bit_cast(
      float, __builtin_amdgcn_update_dpp(xi, xi, CTRL, 0xF, 0xF, false));
}
template <int OFS>
DEV float swz(float x) {
  return __builtin_bit_cast(
      float, __builtin_amdgcn_ds_swizzle(__builtin_bit_cast(int, x), OFS));
}

template <int M>  // value at lane^M
DEV float partner(float x) {
  if constexpr (M == 32) return shx(x, 32);
  else if constexpr (M == 16) return swz<0x401F>(x);
  else if constexpr (M == 8) return dppx<0x128>(x);
  else if constexpr (M == 4) return swz<0x101F>(x);
  else if constexpr (M == 2) return dppx<0x4E>(x);
  else return dppx<0xB1>(x);
}

// ---------------- Rot gates (both samples, coeffs shared) -------------------

template <int M>
DEV void rot_partg(float (&re)[2][16], float (&im)[2][16], int lane,
                   float u00r, float u00i, float u01r, float u01i,
                   float u10r, float u10i, float u11r, float u11i) {
  const bool hi = (lane & M) != 0;
  float Dor = hi ? u11r : u00r, Doi = hi ? u11i : u00i;
  float Dpr = hi ? u10r : u01r, Dpi = hi ? u10i : u01i;
#pragma unroll
  for (int j = 0; j < 16; ++j) {
#pragma unroll
    for (int s = 0; s < 2; ++s) {
      float pr = partner<M>(re[s][j]), pi = partner<M>(im[s][j]);
      float nr = Dor * re[s][j] - Doi * im[s][j] + Dpr * pr - Dpi * pi;
      float ni = Dor * im[s][j] + Doi * re[s][j] + Dpr * pi + Dpi * pr;
      re[s][j] = nr; im[s][j] = ni;
    }
  }
}

template <int M>
DEV void gate_local_c(float (&re)[2][16], float (&im)[2][16],
                      float u00r, float u00i, float u01r, float u01i,
                      float u10r, float u10i, float u11r, float u11i) {
#pragma unroll
  for (int j = 0; j < 16; ++j) {
    if (j & M) continue;
    const int k = j | M;
#pragma unroll
    for (int s = 0; s < 2; ++s) {
      float a0r = re[s][j], a0i = im[s][j], a1r = re[s][k], a1i = im[s][k];
      re[s][j] = u00r * a0r - u00i * a0i + u01r * a1r - u01i * a1i;
      im[s][j] = u00r * a0i + u00i * a0r + u01r * a1i + u01i * a1r;
      re[s][k] = u10r * a0r - u10i * a0i + u11r * a1r - u11i * a1i;
      im[s][k] = u10r * a0i + u10i * a0r + u11r * a1i + u11i * a1r;
    }
  }
}

// ---------------- CNOTs ------------------------------------------------------

template <int CM, int TM>  // control lane bit CM, target lane bit TM
DEV void cnot_part(float (&re)[2][16], float (&im)[2][16], int lane) {
  const bool c = (lane & CM) != 0;
#pragma unroll
  for (int j = 0; j < 16; ++j) {
#pragma unroll
    for (int s = 0; s < 2; ++s) {
      float pr = partner<TM>(re[s][j]), pi = partner<TM>(im[s][j]);
      re[s][j] = c ? pr : re[s][j];
      im[s][j] = c ? pi : im[s][j];
    }
  }
}

// ctrl = lane bit1, tgt = lane bit0: single quad_perm [0,1,3,2]
DEV void cnot_quad(float (&re)[2][16], float (&im)[2][16]) {
#pragma unroll
  for (int j = 0; j < 16; ++j) {
#pragma unroll
    for (int s = 0; s < 2; ++s) {
      re[s][j] = dppx<0xB4>(re[s][j]);
      im[s][j] = dppx<0xB4>(im[s][j]);
    }
  }
}

template <int CM, int TM>  // control = lane bit, target = local bit
DEV void cnot_lane_local(float (&re)[2][16], float (&im)[2][16], int lane) {
  const bool ctrl = (lane & CM) != 0;
#pragma unroll
  for (int j = 0; j < 16; ++j) {
    if (j & TM) continue;
    const int k = j | TM;
#pragma unroll
    for (int s = 0; s < 2; ++s) {
      float tr = re[s][j], ti = im[s][j];
      re[s][j] = ctrl ? re[s][k] : re[s][j];
      im[s][j] = ctrl ? im[s][k] : im[s][j];
      re[s][k] = ctrl ? tr : re[s][k];
      im[s][k] = ctrl ? ti : im[s][k];
    }
  }
}

template <int CM, int TM>  // both local: static register swap (free after SSA)
DEV void cnot_local_local(float (&re)[2][16], float (&im)[2][16]) {
#pragma unroll
  for (int j = 0; j < 16; ++j) {
    if ((j & CM) && !(j & TM)) {
      const int k = j | TM;
#pragma unroll
      for (int s = 0; s < 2; ++s) {
        float tr = re[s][j]; re[s][j] = re[s][k]; re[s][k] = tr;
        float ti = im[s][j]; im[s][j] = im[s][k]; im[s][k] = ti;
      }
    }
  }
}

// ---------------- dispatch ---------------------------------------------------

DEV void rot_wire(int w, float (&re)[2][16], float (&im)[2][16], int lane,
                  const float* __restrict__ pp) {
  // PennyLane Rot = RZ(om) @ RY(th) @ RZ(ph)
  float ph = pp[0], th = pp[1], om = pp[2];
  float s, c;   __sincosf(0.5f * th, &s, &c);
  float sa, ca; __sincosf(0.5f * (ph + om), &sa, &ca);
  float sb, cb; __sincosf(0.5f * (ph - om), &sb, &cb);
  float u00r = c * ca, u00i = -c * sa;
  float u01r = -s * cb, u01i = -s * sb;
  float u10r = s * cb, u10i = -s * sb;
  float u11r = c * ca, u11i = c * sa;
  switch (w) {
    case 0: rot_partg<32>(re, im, lane, u00r, u00i, u01r, u01i, u10r, u10i, u11r, u11i); break;
    case 1: rot_partg<16>(re, im, lane, u00r, u00i, u01r, u01i, u10r, u10i, u11r, u11i); break;
    case 2: rot_partg<8>(re, im, lane, u00r, u00i, u01r, u01i, u10r, u10i, u11r, u11i); break;
    case 3: rot_partg<4>(re, im, lane, u00r, u00i, u01r, u01i, u10r, u10i, u11r, u11i); break;
    case 4: rot_partg<2>(re, im, lane, u00r, u00i, u01r, u01i, u10r, u10i, u11r, u11i); break;
    case 5: rot_partg<1>(re, im, lane, u00r, u00i, u01r, u01i, u10r, u10i, u11r, u11i); break;
    case 6: gate_local_c<8>(re, im, u00r, u00i, u01r, u01i, u10r, u10i, u11r, u11i); break;
    case 7: gate_local_c<4>(re, im, u00r, u00i, u01r, u01i, u10r, u10i, u11r, u11i); break;
    case 8: gate_local_c<2>(re, im, u00r, u00i, u01r, u01i, u10r, u10i, u11r, u11i); break;
    case 9: gate_local_c<1>(re, im, u00r, u00i, u01r, u01i, u10r, u10i, u11r, u11i); break;
  }
}

DEV void cnot_wire(int w, float (&re)[2][16], float (&im)[2][16], int lane) {
  switch (w) {
    case 0: cnot_part<32, 16>(re, im, lane); break;
    case 1: cnot_part<16, 8>(re, im, lane); break;
    case 2: cnot_part<8, 4>(re, im, lane); break;
    case 3: cnot_part<4, 2>(re, im, lane); break;
    case 4: cnot_quad(re, im); break;  // ctrl bit1, tgt bit0
    case 5: cnot_lane_local<1, 8>(re, im, lane); break;
    case 6: cnot_local_local<8, 4>(re, im); break;
    case 7: cnot_local_local<4, 2>(re, im); break;
    case 8: cnot_local_local<2, 1>(re, im); break;
  }
}

// ---------------- X features -------------------------------------------------
// partner form double-counts each (0,1) pair across the lane-sum -> equals 2*Re

template <int M>
DEV float xfeat_part(const float (&re)[16], const float (&im)[16]) {
  float t = 0.f;
#pragma unroll
  for (int j = 0; j < 16; ++j)
    t += re[j] * partner<M>(re[j]) + im[j] * partner<M>(im[j]);
  return t;
}

// ---------------- kernel -----------------------------------------------------

__global__ __launch_bounds__(256) void qreg_kernel(
    const float* __restrict__ x,      // (B, 10)
    const float* __restrict__ params, // (60,)
    const float* __restrict__ hw,     // (20,)
    const float* __restrict__ hb,     // (1,)
    float* __restrict__ out,          // (B,)
    int Bn) {
  const int lane = threadIdx.x & 63;
  const int b0 = blockIdx.x * 8 + (threadIdx.x >> 6) * 2;
  if (b0 >= Bn) return;
  const int b1 = b0 + 1;
  const int b1r = (b1 < Bn) ? b1 : b0;  // clamp read for odd tail

  float re[2][16], im[2][16];

  // ---- encoding: build the RY product state directly ----
  // amp[i] = prod_w f_w(bit_w(i)); f_w(0)=cos(x_w/2), f_w(1)=sin(x_w/2)
#pragma unroll
  for (int s = 0; s < 2; ++s) {
    const int bs = s ? b1r : b0;
    float c_[10], s_[10];
#pragma unroll
    for (int w = 0; w < 10; ++w)
      __sincosf(0.5f * x[bs * 10 + w], &s_[w], &c_[w]);
    // lane factor: wires 0..5 <-> lane bits 5..0
    float L = (lane & 32) ? s_[0] : c_[0];
    L *= (lane & 16) ? s_[1] : c_[1];
    L *= (lane & 8) ? s_[2] : c_[2];
    L *= (lane & 4) ? s_[3] : c_[3];
    L *= (lane & 2) ? s_[4] : c_[4];
    L *= (lane & 1) ? s_[5] : c_[5];
    // local table: j bit3..0 <-> wires 6..9
    float t2[4], t3[8];
    t2[0] = c_[8] * c_[9]; t2[1] = c_[8] * s_[9];
    t2[2] = s_[8] * c_[9]; t2[3] = s_[8] * s_[9];
#pragma unroll
    for (int j = 0; j < 8; ++j) t3[j] = ((j & 4) ? s_[7] : c_[7]) * t2[j & 3];
#pragma unroll
    for (int j = 0; j < 16; ++j) {
      re[s][j] = L * ((j & 8) ? s_[6] : c_[6]) * t3[j & 7];
      im[s][j] = 0.f;
    }
  }

  // ---- 2 layers of Rot + CNOT chain (params shared across samples) ----
#pragma unroll
  for (int l = 0; l < 2; ++l) {
#pragma unroll
    for (int w = 0; w < 10; ++w)
      rot_wire(w, re, im, lane, params + (l * 10 + w) * 3);
#pragma unroll
    for (int w = 0; w < 9; ++w)
      cnot_wire(w, re, im, lane);
  }

  // ---- features folded into head dot-product ----
  float accs[2];
#pragma unroll
  for (int s = 0; s < 2; ++s) {
    float p_[16];
    float S = 0.f;
#pragma unroll
    for (int j = 0; j < 16; ++j) {
      p_[j] = re[s][j] * re[s][j] + im[s][j] * im[s][j];
      S += p_[j];
    }
    float acc = 0.f;
    // <Z_w>, lane wires 0..5: sign uniform per lane
#pragma unroll
    for (int w = 0; w < 6; ++w) {
      const int m = 1 << (5 - w);
      acc += hw[w] * ((lane & m) ? -S : S);
    }
    // <Z_w>, local wires 6..9
#pragma unroll
    for (int w = 6; w < 10; ++w) {
      const int m = 1 << (9 - w);
      float t = 0.f;
#pragma unroll
      for (int j = 0; j < 16; ++j) t += (j & m) ? -p_[j] : p_[j];
      acc += hw[w] * t;
    }
    // <X_w>, lane wires 0..5
    acc += hw[10] * xfeat_part<32>(re[s], im[s]);
    acc += hw[11] * xfeat_part<16>(re[s], im[s]);
    acc += hw[12] * xfeat_part<8>(re[s], im[s]);
    acc += hw[13] * xfeat_part<4>(re[s], im[s]);
    acc += hw[14] * xfeat_part<2>(re[s], im[s]);
    acc += hw[15] * xfeat_part<1>(re[s], im[s]);
    // <X_w>, local wires 6..9 (j and j^m both iterate -> implicit x2)
#pragma unroll
    for (int w = 6; w < 10; ++w) {
      const int m = 1 << (9 - w);
      float t = 0.f;
#pragma unroll
      for (int j = 0; j < 16; ++j)
        t += re[s][j] * re[s][j ^ m] + im[s][j] * im[s][j ^ m];
      acc += hw[10 + w] * t;
    }
    // butterfly reduction over the wave
    acc += partner<32>(acc);
    acc += partner<16>(acc);
    acc += partner<8>(acc);
    acc += partner<4>(acc);
    acc += partner<2>(acc);
    acc += partner<1>(acc);
    accs[s] = acc;
  }

  if (lane == 0) {
    out[b0] = accs[0] + hb[0];
    if (b1 < Bn) out[b1] = accs[1] + hb[0];
  }
}

extern "C" void kernel_launch(void* const* d_in, const int* in_sizes, int n_in,
                              void* d_out, int out_size, void* d_ws, size_t ws_size,
                              hipStream_t stream) {
  const float* x      = (const float*)d_in[0];
  const float* params = (const float*)d_in[1];
  const float* hw     = (const float*)d_in[2];
  const float* hb     = (const float*)d_in[3];
  float* out = (float*)d_out;
  const int B = in_sizes[0] / 10;
  const int blocks = (B + 7) / 8;  // 4 waves/block, 2 samples/wave
  qreg_kernel<<<blocks, 256, 0, stream>>>(x, params, hw, hb, out, B);
}

// Round 9
// 33.141 us; speedup vs baseline: 1.8814x; 1.8814x over previous
//
#include <hip/hip_runtime.h>

#define DEV __device__ __forceinline__

// One wave (64 lanes) simulates one sample's 1024-amplitude state.
// flat idx = lane*16 + j ; wire w <-> flat bit (9-w):
//   wires 0..5 -> lane bits 5..0 (masks 32,16,8,4,2,1)
//   wires 6..8 -> local j bits 3..1 -> packed-slot jj bits 2..0 (masks 4,2,1)
//   wire  9    -> j bit 0 = float2 component (intra-vector)
//
// State is packed: f2 re[8], im[8]; slot jj = {j=2jj (x), j=2jj+1 (y)}.
// Packed fp32 (v_pk_fma_f32, full-rate on gfx90a+/gfx950) halves gate-math
// issue count. Cross-lane partner exchange (all HW-verified R7/R8):
//   mask 32 : __shfl_xor(v,32)
//   mask 16 : ds_swizzle 0x401F   mask 8 : DPP row_ror:8 (0x128)
//   mask 4  : ds_swizzle 0x101F   mask 2 : DPP 0x4E   mask 1 : DPP 0xB1
//   CNOT(ctrl=lane bit1, tgt=bit0): DPP quad_perm [0,1,3,2] (0xB4)

typedef float f2 __attribute__((ext_vector_type(2)));

DEV float shx(float v, int m) { return __shfl_xor(v, m, 64); }

template <int CTRL>
DEV float dppx(float x) {
  int xi = __builtin_bit_cast(int, x);
  return __builtin_bit_cast(
      float, __builtin_amdgcn_update_dpp(xi, xi, CTRL, 0xF, 0xF, false));
}
template <int OFS>
DEV float swz(float x) {
  return __builtin_bit_cast(
      float, __builtin_amdgcn_ds_swizzle(__builtin_bit_cast(int, x), OFS));
}

template <int M>  // scalar value at lane^M
DEV float partner(float x) {
  if constexpr (M == 32) return shx(x, 32);
  else if constexpr (M == 16) return swz<0x401F>(x);
  else if constexpr (M == 8) return dppx<0x128>(x);
  else if constexpr (M == 4) return swz<0x101F>(x);
  else if constexpr (M == 2) return dppx<0x4E>(x);
  else return dppx<0xB1>(x);
}

template <int M>
DEV f2 partner2(f2 v) { return (f2){partner<M>(v.x), partner<M>(v.y)}; }

DEV f2 swp(f2 v) { return (f2){v.y, v.x}; }

// ---------------- Rot gates --------------------------------------------------

// lane-bit gate, packed slots
template <int M>
DEV void rot_partg(f2 (&re)[8], f2 (&im)[8], int lane,
                   float u00r, float u00i, float u01r, float u01i,
                   float u10r, float u10i, float u11r, float u11i) {
  const bool hi = (lane & M) != 0;
  float Dor = hi ? u11r : u00r, Doi = hi ? u11i : u00i;
  float Dpr = hi ? u10r : u01r, Dpi = hi ? u10i : u01i;
#pragma unroll
  for (int jj = 0; jj < 8; ++jj) {
    f2 pr = partner2<M>(re[jj]), pi = partner2<M>(im[jj]);
    f2 nr = Dor * re[jj] - Doi * im[jj] + Dpr * pr - Dpi * pi;
    f2 ni = Dor * im[jj] + Doi * re[jj] + Dpr * pi + Dpi * pr;
    re[jj] = nr; im[jj] = ni;
  }
}

// local-bit gate on packed-slot mask M2 (wires 6..8)
template <int M2>
DEV void rot_local(f2 (&re)[8], f2 (&im)[8],
                   float u00r, float u00i, float u01r, float u01i,
                   float u10r, float u10i, float u11r, float u11i) {
#pragma unroll
  for (int jj = 0; jj < 8; ++jj) {
    if (jj & M2) continue;
    const int k = jj | M2;
    f2 a0r = re[jj], a0i = im[jj], a1r = re[k], a1i = im[k];
    re[jj] = u00r * a0r - u00i * a0i + u01r * a1r - u01i * a1i;
    im[jj] = u00r * a0i + u00i * a0r + u01r * a1i + u01i * a1r;
    re[k]  = u10r * a0r - u10i * a0i + u11r * a1r - u11i * a1i;
    im[k]  = u10r * a0i + u10i * a0r + u11r * a1i + u11i * a1r;
  }
}

// wire-9 gate: intra-vector (component 0 = bit0=0, component 1 = bit0=1)
DEV void rot_vec(f2 (&re)[8], f2 (&im)[8],
                 float u00r, float u00i, float u01r, float u01i,
                 float u10r, float u10i, float u11r, float u11i) {
  const f2 Vor = (f2){u00r, u11r}, Voi = (f2){u00i, u11i};
  const f2 Vpr = (f2){u01r, u10r}, Vpi = (f2){u01i, u10i};
#pragma unroll
  for (int jj = 0; jj < 8; ++jj) {
    f2 sr = swp(re[jj]), si = swp(im[jj]);
    f2 nr = Vor * re[jj] - Voi * im[jj] + Vpr * sr - Vpi * si;
    f2 ni = Vor * im[jj] + Voi * re[jj] + Vpr * si + Vpi * sr;
    re[jj] = nr; im[jj] = ni;
  }
}

// ---------------- CNOTs ------------------------------------------------------

template <int CM, int TM>  // control lane bit CM, target lane bit TM
DEV void cnot_part(f2 (&re)[8], f2 (&im)[8], int lane) {
  const bool c = (lane & CM) != 0;
#pragma unroll
  for (int jj = 0; jj < 8; ++jj) {
    f2 pr = partner2<TM>(re[jj]), pi = partner2<TM>(im[jj]);
    re[jj] = c ? pr : re[jj];
    im[jj] = c ? pi : im[jj];
  }
}

// ctrl = lane bit1, tgt = lane bit0: single quad_perm [0,1,3,2] per word
DEV void cnot_quad(f2 (&re)[8], f2 (&im)[8]) {
#pragma unroll
  for (int jj = 0; jj < 8; ++jj) {
    re[jj] = (f2){dppx<0xB4>(re[jj].x), dppx<0xB4>(re[jj].y)};
    im[jj] = (f2){dppx<0xB4>(im[jj].x), dppx<0xB4>(im[jj].y)};
  }
}

template <int CM, int TM2>  // control = lane bit, target = packed-slot bit
DEV void cnot_lane_local(f2 (&re)[8], f2 (&im)[8], int lane) {
  const bool ctrl = (lane & CM) != 0;
#pragma unroll
  for (int jj = 0; jj < 8; ++jj) {
    if (jj & TM2) continue;
    const int k = jj | TM2;
    f2 tr = re[jj], ti = im[jj];
    re[jj] = ctrl ? re[k] : re[jj];
    im[jj] = ctrl ? im[k] : im[jj];
    re[k]  = ctrl ? tr : re[k];
    im[k]  = ctrl ? ti : im[k];
  }
}

template <int CM2, int TM2>  // both packed-slot bits: static swap (SSA-free)
DEV void cnot_local_local(f2 (&re)[8], f2 (&im)[8]) {
#pragma unroll
  for (int jj = 0; jj < 8; ++jj) {
    if ((jj & CM2) && !(jj & TM2)) {
      const int k = jj | TM2;
      f2 tr = re[jj]; re[jj] = re[k]; re[k] = tr;
      f2 ti = im[jj]; im[jj] = im[k]; im[k] = ti;
    }
  }
}

// control = packed-slot bit1 (wire 8), target = intra-vector (wire 9)
DEV void cnot_vec(f2 (&re)[8], f2 (&im)[8]) {
#pragma unroll
  for (int jj = 0; jj < 8; ++jj) {
    if (jj & 1) { re[jj] = swp(re[jj]); im[jj] = swp(im[jj]); }
  }
}

// ---------------- dispatch ---------------------------------------------------

DEV void rot_wire(int w, f2 (&re)[8], f2 (&im)[8], int lane,
                  const float* __restrict__ pp) {
  // PennyLane Rot = RZ(om) @ RY(th) @ RZ(ph)
  float ph = pp[0], th = pp[1], om = pp[2];
  float s, c;   __sincosf(0.5f * th, &s, &c);
  float sa, ca; __sincosf(0.5f * (ph + om), &sa, &ca);
  float sb, cb; __sincosf(0.5f * (ph - om), &sb, &cb);
  float u00r = c * ca, u00i = -c * sa;
  float u01r = -s * cb, u01i = -s * sb;
  float u10r = s * cb, u10i = -s * sb;
  float u11r = c * ca, u11i = c * sa;
  switch (w) {
    case 0: rot_partg<32>(re, im, lane, u00r, u00i, u01r, u01i, u10r, u10i, u11r, u11i); break;
    case 1: rot_partg<16>(re, im, lane, u00r, u00i, u01r, u01i, u10r, u10i, u11r, u11i); break;
    case 2: rot_partg<8>(re, im, lane, u00r, u00i, u01r, u01i, u10r, u10i, u11r, u11i); break;
    case 3: rot_partg<4>(re, im, lane, u00r, u00i, u01r, u01i, u10r, u10i, u11r, u11i); break;
    case 4: rot_partg<2>(re, im, lane, u00r, u00i, u01r, u01i, u10r, u10i, u11r, u11i); break;
    case 5: rot_partg<1>(re, im, lane, u00r, u00i, u01r, u01i, u10r, u10i, u11r, u11i); break;
    case 6: rot_local<4>(re, im, u00r, u00i, u01r, u01i, u10r, u10i, u11r, u11i); break;
    case 7: rot_local<2>(re, im, u00r, u00i, u01r, u01i, u10r, u10i, u11r, u11i); break;
    case 8: rot_local<1>(re, im, u00r, u00i, u01r, u01i, u10r, u10i, u11r, u11i); break;
    case 9: rot_vec(re, im, u00r, u00i, u01r, u01i, u10r, u10i, u11r, u11i); break;
  }
}

DEV void cnot_wire(int w, f2 (&re)[8], f2 (&im)[8], int lane) {
  switch (w) {
    case 0: cnot_part<32, 16>(re, im, lane); break;
    case 1: cnot_part<16, 8>(re, im, lane); break;
    case 2: cnot_part<8, 4>(re, im, lane); break;
    case 3: cnot_part<4, 2>(re, im, lane); break;
    case 4: cnot_quad(re, im); break;            // ctrl lane bit1, tgt bit0
    case 5: cnot_lane_local<1, 4>(re, im, lane); break;
    case 6: cnot_local_local<4, 2>(re, im); break;
    case 7: cnot_local_local<2, 1>(re, im); break;
    case 8: cnot_vec(re, im); break;             // ctrl jj bit0, tgt component
  }
}

// ---------------- X features (lane wires) ------------------------------------
// partner form double-counts each (0,1) pair across the lane-sum -> equals 2*Re

template <int M>
DEV float xfeat_part(const f2 (&re)[8], const f2 (&im)[8]) {
  f2 t = (f2){0.f, 0.f};
#pragma unroll
  for (int jj = 0; jj < 8; ++jj)
    t += re[jj] * partner2<M>(re[jj]) + im[jj] * partner2<M>(im[jj]);
  return t.x + t.y;
}

// ---------------- kernel -----------------------------------------------------

__global__ __launch_bounds__(256) void qreg_kernel(
    const float* __restrict__ x,      // (B, 10)
    const float* __restrict__ params, // (60,)
    const float* __restrict__ hw,     // (20,)
    const float* __restrict__ hb,     // (1,)
    float* __restrict__ out,          // (B,)
    int Bn) {
  const int lane = threadIdx.x & 63;
  const int b = blockIdx.x * 4 + (threadIdx.x >> 6);
  if (b >= Bn) return;

  f2 re[8], im[8];

  // ---- encoding: build the RY product state directly (verified in R8) ----
  // amp[i] = prod_w f_w(bit_w(i)); f_w(0)=cos(x_w/2), f_w(1)=sin(x_w/2)
  {
    float c_[10], s_[10];
#pragma unroll
    for (int w = 0; w < 10; ++w)
      __sincosf(0.5f * x[b * 10 + w], &s_[w], &c_[w]);
    float L = (lane & 32) ? s_[0] : c_[0];
    L *= (lane & 16) ? s_[1] : c_[1];
    L *= (lane & 8) ? s_[2] : c_[2];
    L *= (lane & 4) ? s_[3] : c_[3];
    L *= (lane & 2) ? s_[4] : c_[4];
    L *= (lane & 1) ? s_[5] : c_[5];
    float t2[4], t3[8], t4[16];
    t2[0] = c_[8] * c_[9]; t2[1] = c_[8] * s_[9];
    t2[2] = s_[8] * c_[9]; t2[3] = s_[8] * s_[9];
#pragma unroll
    for (int j = 0; j < 8; ++j) t3[j] = ((j & 4) ? s_[7] : c_[7]) * t2[j & 3];
#pragma unroll
    for (int j = 0; j < 16; ++j) t4[j] = L * ((j & 8) ? s_[6] : c_[6]) * t3[j & 7];
#pragma unroll
    for (int jj = 0; jj < 8; ++jj) {
      re[jj] = (f2){t4[2 * jj], t4[2 * jj + 1]};
      im[jj] = (f2){0.f, 0.f};
    }
  }

  // ---- 2 layers of Rot + CNOT chain (shared params) ----
#pragma unroll
  for (int l = 0; l < 2; ++l) {
#pragma unroll
    for (int w = 0; w < 10; ++w)
      rot_wire(w, re, im, lane, params + (l * 10 + w) * 3);
#pragma unroll
    for (int w = 0; w < 9; ++w)
      cnot_wire(w, re, im, lane);
  }

  // ---- features folded into head dot-product ----
  f2 Sv = (f2){0.f, 0.f}, z6 = (f2){0.f, 0.f}, z7 = (f2){0.f, 0.f},
     z8 = (f2){0.f, 0.f};
  float z9 = 0.f;
#pragma unroll
  for (int jj = 0; jj < 8; ++jj) {
    f2 pf = re[jj] * re[jj] + im[jj] * im[jj];
    Sv += pf;
    z6 += (jj & 4) ? -pf : pf;
    z7 += (jj & 2) ? -pf : pf;
    z8 += (jj & 1) ? -pf : pf;
    z9 += pf.x - pf.y;
  }
  const float S = Sv.x + Sv.y;
  float acc = 0.f;
  // <Z_w>, lane wires 0..5: sign uniform per lane
#pragma unroll
  for (int w = 0; w < 6; ++w) {
    const int m = 1 << (5 - w);
    acc += hw[w] * ((lane & m) ? -S : S);
  }
  // <Z_w>, local wires 6..9
  acc += hw[6] * (z6.x + z6.y);
  acc += hw[7] * (z7.x + z7.y);
  acc += hw[8] * (z8.x + z8.y);
  acc += hw[9] * z9;
  // <X_w>, lane wires 0..5
  acc += hw[10] * xfeat_part<32>(re, im);
  acc += hw[11] * xfeat_part<16>(re, im);
  acc += hw[12] * xfeat_part<8>(re, im);
  acc += hw[13] * xfeat_part<4>(re, im);
  acc += hw[14] * xfeat_part<2>(re, im);
  acc += hw[15] * xfeat_part<1>(re, im);
  // <X_w>, local wires 6..8 (jj and jj^m both iterate -> implicit x2)
  {
    f2 x6 = (f2){0.f, 0.f}, x7 = (f2){0.f, 0.f}, x8 = (f2){0.f, 0.f};
    float x9 = 0.f;
#pragma unroll
    for (int jj = 0; jj < 8; ++jj) {
      x6 += re[jj] * re[jj ^ 4] + im[jj] * im[jj ^ 4];
      x7 += re[jj] * re[jj ^ 2] + im[jj] * im[jj ^ 2];
      x8 += re[jj] * re[jj ^ 1] + im[jj] * im[jj ^ 1];
      x9 += re[jj].x * re[jj].y + im[jj].x * im[jj].y;  // wire 9: intra-vector
    }
    acc += hw[16] * (x6.x + x6.y);
    acc += hw[17] * (x7.x + x7.y);
    acc += hw[18] * (x8.x + x8.y);
    acc += hw[19] * (2.f * x9);
  }

  // butterfly reduction over the wave (verified partner primitives)
  acc += partner<32>(acc);
  acc += partner<16>(acc);
  acc += partner<8>(acc);
  acc += partner<4>(acc);
  acc += partner<2>(acc);
  acc += partner<1>(acc);
  if (lane == 0) out[b] = acc + hb[0];
}

extern "C" void kernel_launch(void* const* d_in, const int* in_sizes, int n_in,
                              void* d_out, int out_size, void* d_ws, size_t ws_size,
                              hipStream_t stream) {
  const float* x      = (const float*)d_in[0];
  const float* params = (const float*)d_in[1];
  const float* hw     = (const float*)d_in[2];
  const float* hb     = (const float*)d_in[3];
  float* out = (float*)d_out;
  const int B = in_sizes[0] / 10;
  const int blocks = (B + 3) / 4;  // 4 waves/block, 1 sample/wave
  qreg_kernel<<<blocks, 256, 0, stream>>>(x, params, hw, hb, out, B);
}

// Round 10
// 28.731 us; speedup vs baseline: 2.1702x; 1.1535x over previous
//
#include <hip/hip_runtime.h>

#define DEV __device__ __forceinline__

// One wave (64 lanes) simulates one sample's 1024-amplitude state.
// flat idx = lane*16 + j ; wire w <-> flat bit (9-w):
//   wires 0..5 -> lane bits 5..0 (masks 32,16,8,4,2,1)
//   wires 6..8 -> packed-slot jj bits 2..0 (masks 4,2,1);  wire 9 -> component
// State: f2 re[8], im[8] (packed fp32, v_pk_fma_f32 full-rate).
//
// CNOT chains are never materialized. The chain is the linear map
// PHI(x)_v = x_v ^ x_{v-1} (wire order), final[i] = pre[PHI(i)].
// Layer-2 gates are conjugated: pair mask PHI(e_w)=e_w^e_{w+1},
// row selector = prefix parity p_w(k). Features see PHI^2:
// Z_w sign = parity{u<=w, w-u even}; X_w mask = e_w^e_{w+2} (e_w for w>=8).
//
// Cross-lane primitives (HW-verified R7/R9): shfl_xor; ds_swizzle bit-mode
// (xor<=31): offset=(xor<<10)|0x1F; DPP quad_perm/row_ror.

typedef float f2 __attribute__((ext_vector_type(2)));

DEV float shx(float v, int m) { return __shfl_xor(v, m, 64); }

template <int CTRL>
DEV float dppx(float x) {
  int xi = __builtin_bit_cast(int, x);
  return __builtin_bit_cast(
      float, __builtin_amdgcn_update_dpp(xi, xi, CTRL, 0xF, 0xF, false));
}
template <int OFS>
DEV float swz(float x) {
  return __builtin_bit_cast(
      float, __builtin_amdgcn_ds_swizzle(__builtin_bit_cast(int, x), OFS));
}

template <int M>  // scalar value at lane^M (single-bit masks)
DEV float partner(float x) {
  if constexpr (M == 32) return shx(x, 32);
  else if constexpr (M == 16) return swz<0x401F>(x);
  else if constexpr (M == 8) return dppx<0x128>(x);
  else if constexpr (M == 4) return swz<0x101F>(x);
  else if constexpr (M == 2) return dppx<0x4E>(x);
  else return dppx<0xB1>(x);
}
template <int M>
DEV f2 partner2(f2 v) { return (f2){partner<M>(v.x), partner<M>(v.y)}; }

template <int XM>  // generic lane-xor exchange (multi-bit masks)
DEV float lanex(float x) {
  if constexpr (XM == 48) return shx(x, 48);
  else if constexpr (XM == 40) return shx(x, 40);
  else if constexpr (XM == 24) return swz<0x601F>(x);
  else if constexpr (XM == 20) return swz<0x501F>(x);
  else if constexpr (XM == 12) return swz<0x301F>(x);
  else if constexpr (XM == 10) return swz<0x281F>(x);
  else if constexpr (XM == 6)  return swz<0x181F>(x);
  else if constexpr (XM == 5)  return swz<0x141F>(x);
  else if constexpr (XM == 3)  return swz<0x0C1F>(x);
}
template <int XM>
DEV f2 lanex2(f2 v) { return (f2){lanex<XM>(v.x), lanex<XM>(v.y)}; }

DEV f2 swp(f2 v) { return (f2){v.y, v.x}; }
DEV float dot2(f2 a, f2 b) { f2 t = a * b; return t.x + t.y; }

// ================= layer-1 gates (verified R9) ===============================

template <int M>
DEV void rot_partg(f2 (&re)[8], f2 (&im)[8], int lane,
                   float u00r, float u00i, float u01r, float u01i,
                   float u10r, float u10i, float u11r, float u11i) {
  const bool hi = (lane & M) != 0;
  float Dor = hi ? u11r : u00r, Doi = hi ? u11i : u00i;
  float Dpr = hi ? u10r : u01r, Dpi = hi ? u10i : u01i;
#pragma unroll
  for (int jj = 0; jj < 8; ++jj) {
    f2 pr = partner2<M>(re[jj]), pi = partner2<M>(im[jj]);
    f2 nr = Dor * re[jj] - Doi * im[jj] + Dpr * pr - Dpi * pi;
    f2 ni = Dor * im[jj] + Doi * re[jj] + Dpr * pi + Dpi * pr;
    re[jj] = nr; im[jj] = ni;
  }
}

template <int M2>
DEV void rot_local(f2 (&re)[8], f2 (&im)[8],
                   float u00r, float u00i, float u01r, float u01i,
                   float u10r, float u10i, float u11r, float u11i) {
#pragma unroll
  for (int jj = 0; jj < 8; ++jj) {
    if (jj & M2) continue;
    const int k = jj | M2;
    f2 a0r = re[jj], a0i = im[jj], a1r = re[k], a1i = im[k];
    re[jj] = u00r * a0r - u00i * a0i + u01r * a1r - u01i * a1i;
    im[jj] = u00r * a0i + u00i * a0r + u01r * a1i + u01i * a1r;
    re[k]  = u10r * a0r - u10i * a0i + u11r * a1r - u11i * a1i;
    im[k]  = u10r * a0i + u10i * a0r + u11r * a1i + u11i * a1r;
  }
}

DEV void rot_vec(f2 (&re)[8], f2 (&im)[8],
                 float u00r, float u00i, float u01r, float u01i,
                 float u10r, float u10i, float u11r, float u11i) {
  const f2 Vor = (f2){u00r, u11r}, Voi = (f2){u00i, u11i};
  const f2 Vpr = (f2){u01r, u10r}, Vpi = (f2){u01i, u10i};
#pragma unroll
  for (int jj = 0; jj < 8; ++jj) {
    f2 sr = swp(re[jj]), si = swp(im[jj]);
    f2 nr = Vor * re[jj] - Voi * im[jj] + Vpr * sr - Vpi * si;
    f2 ni = Vor * im[jj] + Voi * re[jj] + Vpr * si + Vpi * sr;
    re[jj] = nr; im[jj] = ni;
  }
}

// ================= layer-2 gates (conjugated by PHI) =========================

// wires 0..4: pair mask XM (two lane bits), selector parity(lane & SELM)
template <int XM, int SELM>
DEV void rot2_lane(f2 (&re)[8], f2 (&im)[8], int lane,
                   float u00r, float u00i, float u01r, float u01i,
                   float u10r, float u10i, float u11r, float u11i) {
  const bool hi = (__popc(lane & SELM) & 1) != 0;
  float Dor = hi ? u11r : u00r, Doi = hi ? u11i : u00i;
  float Dpr = hi ? u10r : u01r, Dpi = hi ? u10i : u01i;
#pragma unroll
  for (int jj = 0; jj < 8; ++jj) {
    f2 pr = lanex2<XM>(re[jj]), pi = lanex2<XM>(im[jj]);
    f2 nr = Dor * re[jj] - Doi * im[jj] + Dpr * pr - Dpi * pi;
    f2 ni = Dor * im[jj] + Doi * re[jj] + Dpr * pi + Dpi * pr;
    re[jj] = nr; im[jj] = ni;
  }
}

// wire 5: pair = (lane^1, jj^4), selector p5 (lane-uniform)
DEV void rot2_w5(f2 (&re)[8], f2 (&im)[8], bool p5,
                 float u00r, float u00i, float u01r, float u01i,
                 float u10r, float u10i, float u11r, float u11i) {
  float Dor = p5 ? u11r : u00r, Doi = p5 ? u11i : u00i;
  float Dpr = p5 ? u10r : u01r, Dpi = p5 ? u10i : u01i;
  f2 o_r[8], o_i[8];
#pragma unroll
  for (int jj = 0; jj < 8; ++jj) { o_r[jj] = re[jj]; o_i[jj] = im[jj]; }
#pragma unroll
  for (int jj = 0; jj < 8; ++jj) {
    const int k = jj ^ 4;
    f2 pr = partner2<1>(o_r[k]), pi = partner2<1>(o_i[k]);
    re[jj] = Dor * o_r[jj] - Doi * o_i[jj] + Dpr * pr - Dpi * pi;
    im[jj] = Dor * o_i[jj] + Doi * o_r[jj] + Dpr * pi + Dpi * pr;
  }
}

// wires 6,7: pair mask M2 on slots, class = parity(jj & CLS), hi = p5 ^ class
template <int M2, int CLS>
DEV void rot2_local(f2 (&re)[8], f2 (&im)[8], bool p5,
                    float u00r, float u00i, float u01r, float u01i,
                    float u10r, float u10i, float u11r, float u11i) {
  const float D0or = p5 ? u11r : u00r, D0oi = p5 ? u11i : u00i;
  const float D0pr = p5 ? u10r : u01r, D0pi = p5 ? u10i : u01i;
  const float D1or = p5 ? u00r : u11r, D1oi = p5 ? u00i : u11i;
  const float D1pr = p5 ? u01r : u10r, D1pi = p5 ? u01i : u10i;
  f2 o_r[8], o_i[8];
#pragma unroll
  for (int jj = 0; jj < 8; ++jj) { o_r[jj] = re[jj]; o_i[jj] = im[jj]; }
#pragma unroll
  for (int jj = 0; jj < 8; ++jj) {
    const int k = jj ^ M2;
    const bool c1 = (__builtin_popcount(jj & CLS) & 1) != 0;
    const float Dor = c1 ? D1or : D0or, Doi = c1 ? D1oi : D0oi;
    const float Dpr = c1 ? D1pr : D0pr, Dpi = c1 ? D1pi : D0pi;
    re[jj] = Dor * o_r[jj] - Doi * o_i[jj] + Dpr * o_r[k] - Dpi * o_i[k];
    im[jj] = Dor * o_i[jj] + Doi * o_r[jj] + Dpr * o_i[k] + Dpi * o_r[k];
  }
}

// wire 8: pair = (jj^1, comp^1), class = parity(jj & 7)
DEV void rot2_w8(f2 (&re)[8], f2 (&im)[8], bool p5,
                 float u00r, float u00i, float u01r, float u01i,
                 float u10r, float u10i, float u11r, float u11i) {
  const float D0or = p5 ? u11r : u00r, D0oi = p5 ? u11i : u00i;
  const float D0pr = p5 ? u10r : u01r, D0pi = p5 ? u10i : u01i;
  const float D1or = p5 ? u00r : u11r, D1oi = p5 ? u00i : u11i;
  const float D1pr = p5 ? u01r : u10r, D1pi = p5 ? u01i : u10i;
  f2 o_r[8], o_i[8];
#pragma unroll
  for (int jj = 0; jj < 8; ++jj) { o_r[jj] = re[jj]; o_i[jj] = im[jj]; }
#pragma unroll
  for (int jj = 0; jj < 8; ++jj) {
    const int k = jj ^ 1;
    const bool c1 = (__builtin_popcount(jj & 7) & 1) != 0;
    const float Dor = c1 ? D1or : D0or, Doi = c1 ? D1oi : D0oi;
    const float Dpr = c1 ? D1pr : D0pr, Dpi = c1 ? D1pi : D0pi;
    f2 pr = swp(o_r[k]), pi = swp(o_i[k]);
    re[jj] = Dor * o_r[jj] - Doi * o_i[jj] + Dpr * pr - Dpi * pi;
    im[jj] = Dor * o_i[jj] + Doi * o_r[jj] + Dpr * pi + Dpi * pr;
  }
}

// wire 9: pair = component, selector p5 ^ parity(jj) ^ comp
DEV void rot2_w9(f2 (&re)[8], f2 (&im)[8], bool p5,
                 float u00r, float u00i, float u01r, float u01i,
                 float u10r, float u10i, float u11r, float u11i) {
  // class0 (parity(jj)=0): comp x row = p5, comp y row = !p5
  const f2 Vor0 = p5 ? (f2){u11r, u00r} : (f2){u00r, u11r};
  const f2 Voi0 = p5 ? (f2){u11i, u00i} : (f2){u00i, u11i};
  const f2 Vpr0 = p5 ? (f2){u10r, u01r} : (f2){u01r, u10r};
  const f2 Vpi0 = p5 ? (f2){u10i, u01i} : (f2){u01i, u10i};
  const f2 Vor1 = p5 ? (f2){u00r, u11r} : (f2){u11r, u00r};
  const f2 Voi1 = p5 ? (f2){u00i, u11i} : (f2){u11i, u00i};
  const f2 Vpr1 = p5 ? (f2){u01r, u10r} : (f2){u10r, u01r};
  const f2 Vpi1 = p5 ? (f2){u01i, u10i} : (f2){u10i, u01i};
#pragma unroll
  for (int jj = 0; jj < 8; ++jj) {
    const bool c1 = (__builtin_popcount(jj) & 1) != 0;
    const f2 Vor = c1 ? Vor1 : Vor0, Voi = c1 ? Voi1 : Voi0;
    const f2 Vpr = c1 ? Vpr1 : Vpr0, Vpi = c1 ? Vpi1 : Vpi0;
    f2 sr = swp(re[jj]), si = swp(im[jj]);
    f2 nr = Vor * re[jj] - Voi * im[jj] + Vpr * sr - Vpi * si;
    f2 ni = Vor * im[jj] + Voi * re[jj] + Vpr * si + Vpi * sr;
    re[jj] = nr; im[jj] = ni;
  }
}

// ================= dispatch ==================================================

DEV void make_u(const float* __restrict__ pp,
                float& u00r, float& u00i, float& u01r, float& u01i,
                float& u10r, float& u10i, float& u11r, float& u11i) {
  // PennyLane Rot = RZ(om) @ RY(th) @ RZ(ph)
  float ph = pp[0], th = pp[1], om = pp[2];
  float s, c;   __sincosf(0.5f * th, &s, &c);
  float sa, ca; __sincosf(0.5f * (ph + om), &sa, &ca);
  float sb, cb; __sincosf(0.5f * (ph - om), &sb, &cb);
  u00r = c * ca;  u00i = -c * sa;
  u01r = -s * cb; u01i = -s * sb;
  u10r = s * cb;  u10i = -s * sb;
  u11r = c * ca;  u11i = c * sa;
}

DEV void rot_wire(int w, f2 (&re)[8], f2 (&im)[8], int lane,
                  const float* __restrict__ pp) {
  float u00r, u00i, u01r, u01i, u10r, u10i, u11r, u11i;
  make_u(pp, u00r, u00i, u01r, u01i, u10r, u10i, u11r, u11i);
  switch (w) {
    case 0: rot_partg<32>(re, im, lane, u00r, u00i, u01r, u01i, u10r, u10i, u11r, u11i); break;
    case 1: rot_partg<16>(re, im, lane, u00r, u00i, u01r, u01i, u10r, u10i, u11r, u11i); break;
    case 2: rot_partg<8>(re, im, lane, u00r, u00i, u01r, u01i, u10r, u10i, u11r, u11i); break;
    case 3: rot_partg<4>(re, im, lane, u00r, u00i, u01r, u01i, u10r, u10i, u11r, u11i); break;
    case 4: rot_partg<2>(re, im, lane, u00r, u00i, u01r, u01i, u10r, u10i, u11r, u11i); break;
    case 5: rot_partg<1>(re, im, lane, u00r, u00i, u01r, u01i, u10r, u10i, u11r, u11i); break;
    case 6: rot_local<4>(re, im, u00r, u00i, u01r, u01i, u10r, u10i, u11r, u11i); break;
    case 7: rot_local<2>(re, im, u00r, u00i, u01r, u01i, u10r, u10i, u11r, u11i); break;
    case 8: rot_local<1>(re, im, u00r, u00i, u01r, u01i, u10r, u10i, u11r, u11i); break;
    case 9: rot_vec(re, im, u00r, u00i, u01r, u01i, u10r, u10i, u11r, u11i); break;
  }
}

DEV void rot2_wire(int w, f2 (&re)[8], f2 (&im)[8], int lane, bool p5,
                   const float* __restrict__ pp) {
  float u00r, u00i, u01r, u01i, u10r, u10i, u11r, u11i;
  make_u(pp, u00r, u00i, u01r, u01i, u10r, u10i, u11r, u11i);
  switch (w) {
    case 0: rot2_lane<48, 32>(re, im, lane, u00r, u00i, u01r, u01i, u10r, u10i, u11r, u11i); break;
    case 1: rot2_lane<24, 48>(re, im, lane, u00r, u00i, u01r, u01i, u10r, u10i, u11r, u11i); break;
    case 2: rot2_lane<12, 56>(re, im, lane, u00r, u00i, u01r, u01i, u10r, u10i, u11r, u11i); break;
    case 3: rot2_lane<6, 60>(re, im, lane, u00r, u00i, u01r, u01i, u10r, u10i, u11r, u11i); break;
    case 4: rot2_lane<3, 62>(re, im, lane, u00r, u00i, u01r, u01i, u10r, u10i, u11r, u11i); break;
    case 5: rot2_w5(re, im, p5, u00r, u00i, u01r, u01i, u10r, u10i, u11r, u11i); break;
    case 6: rot2_local<6, 4>(re, im, p5, u00r, u00i, u01r, u01i, u10r, u10i, u11r, u11i); break;
    case 7: rot2_local<3, 6>(re, im, p5, u00r, u00i, u01r, u01i, u10r, u10i, u11r, u11i); break;
    case 8: rot2_w8(re, im, p5, u00r, u00i, u01r, u01i, u10r, u10i, u11r, u11i); break;
    case 9: rot2_w9(re, im, p5, u00r, u00i, u01r, u01i, u10r, u10i, u11r, u11i); break;
  }
}

// ================= X features (PHI^2 frame) ==================================
// double-count over the full sum equals the required 2*Re(sum over pairs)

template <int XM>
DEV float xfeat_lane(const f2 (&re)[8], const f2 (&im)[8]) {
  f2 t = (f2){0.f, 0.f};
#pragma unroll
  for (int jj = 0; jj < 8; ++jj)
    t += re[jj] * lanex2<XM>(re[jj]) + im[jj] * lanex2<XM>(im[jj]);
  return t.x + t.y;
}

// ================= kernel ====================================================

__global__ __launch_bounds__(256) void qreg_kernel(
    const float* __restrict__ x,      // (B, 10)
    const float* __restrict__ params, // (60,)
    const float* __restrict__ hw,     // (20,)
    const float* __restrict__ hb,     // (1,)
    float* __restrict__ out,          // (B,)
    int Bn) {
  const int lane = threadIdx.x & 63;
  const int b = blockIdx.x * 4 + (threadIdx.x >> 6);
  if (b >= Bn) return;
  const bool p5 = (__popc(lane & 63) & 1) != 0;

  f2 re[8], im[8];

  // ---- encoding: RY product state (verified R8/R9) ----
  {
    float c_[10], s_[10];
#pragma unroll
    for (int w = 0; w < 10; ++w)
      __sincosf(0.5f * x[b * 10 + w], &s_[w], &c_[w]);
    float L = (lane & 32) ? s_[0] : c_[0];
    L *= (lane & 16) ? s_[1] : c_[1];
    L *= (lane & 8) ? s_[2] : c_[2];
    L *= (lane & 4) ? s_[3] : c_[3];
    L *= (lane & 2) ? s_[4] : c_[4];
    L *= (lane & 1) ? s_[5] : c_[5];
    float t2[4], t3[8], t4[16];
    t2[0] = c_[8] * c_[9]; t2[1] = c_[8] * s_[9];
    t2[2] = s_[8] * c_[9]; t2[3] = s_[8] * s_[9];
#pragma unroll
    for (int j = 0; j < 8; ++j) t3[j] = ((j & 4) ? s_[7] : c_[7]) * t2[j & 3];
#pragma unroll
    for (int j = 0; j < 16; ++j) t4[j] = L * ((j & 8) ? s_[6] : c_[6]) * t3[j & 7];
#pragma unroll
    for (int jj = 0; jj < 8; ++jj) {
      re[jj] = (f2){t4[2 * jj], t4[2 * jj + 1]};
      im[jj] = (f2){0.f, 0.f};
    }
  }

  // ---- layer 1: standard Rots (chain handled by frame change) ----
#pragma unroll
  for (int w = 0; w < 10; ++w)
    rot_wire(w, re, im, lane, params + w * 3);

  // ---- layer 2: Rots conjugated by PHI ----
#pragma unroll
  for (int w = 0; w < 10; ++w)
    rot2_wire(w, re, im, lane, p5, params + (10 + w) * 3);

  // ---- features in the PHI^2 frame, folded into head dot-product ----
  f2 Sv = (f2){0.f, 0.f}, t6 = (f2){0.f, 0.f}, t7 = (f2){0.f, 0.f},
     t8 = (f2){0.f, 0.f};
  float t9 = 0.f;
#pragma unroll
  for (int jj = 0; jj < 8; ++jj) {
    f2 pf = re[jj] * re[jj] + im[jj] * im[jj];
    Sv += pf;
    t6 += (jj & 4) ? -pf : pf;
    t7 += (jj & 2) ? -pf : pf;
    t8 += ((__builtin_popcount(jj & 5) & 1)) ? -pf : pf;
    t9 += ((jj & 2) ? -1.f : 1.f) * (pf.x - pf.y);
  }
  const bool pl32 = (lane & 32) != 0, pl16 = (lane & 16) != 0;
  const bool pl40 = (__popc(lane & 40) & 1) != 0;
  const bool pl20 = (__popc(lane & 20) & 1) != 0;
  const bool pl42 = (__popc(lane & 42) & 1) != 0;
  const bool pl21 = (__popc(lane & 21) & 1) != 0;
  const float S_ = Sv.x + Sv.y;
  float acc = 0.f;
  acc += hw[0] * (pl32 ? -S_ : S_);
  acc += hw[1] * (pl16 ? -S_ : S_);
  acc += hw[2] * (pl40 ? -S_ : S_);
  acc += hw[3] * (pl20 ? -S_ : S_);
  acc += hw[4] * (pl42 ? -S_ : S_);
  acc += hw[5] * (pl21 ? -S_ : S_);
  const float t6_ = t6.x + t6.y, t7_ = t7.x + t7.y, t8_ = t8.x + t8.y;
  acc += hw[6] * (pl42 ? -t6_ : t6_);
  acc += hw[7] * (pl21 ? -t7_ : t7_);
  acc += hw[8] * (pl42 ? -t8_ : t8_);
  acc += hw[9] * (pl21 ? -t9 : t9);

  // X_w, wires 0..3: two-bit lane masks 40,20,10,5
  acc += hw[10] * xfeat_lane<40>(re, im);
  acc += hw[11] * xfeat_lane<20>(re, im);
  acc += hw[12] * xfeat_lane<10>(re, im);
  acc += hw[13] * xfeat_lane<5>(re, im);
  // X_4: lane bit1 ^ slot bit2;  X_5: lane bit0 ^ slot bit1
  {
    f2 x4 = (f2){0.f, 0.f}, x5 = (f2){0.f, 0.f};
#pragma unroll
    for (int jj = 0; jj < 8; ++jj) {
      x4 += re[jj] * partner2<2>(re[jj ^ 4]) + im[jj] * partner2<2>(im[jj ^ 4]);
      x5 += re[jj] * partner2<1>(re[jj ^ 2]) + im[jj] * partner2<1>(im[jj ^ 2]);
    }
    acc += hw[14] * (x4.x + x4.y);
    acc += hw[15] * (x5.x + x5.y);
  }
  // X_6: slots jj^5;  X_7: slots jj^2 + comp;  X_8: slots jj^1;  X_9: comp
  {
    f2 x6 = (f2){0.f, 0.f}, x7 = (f2){0.f, 0.f}, x8 = (f2){0.f, 0.f};
    float x9 = 0.f;
#pragma unroll
    for (int jj = 0; jj < 8; ++jj) {
      x6 += re[jj] * re[jj ^ 5] + im[jj] * im[jj ^ 5];
      x7 += re[jj] * swp(re[jj ^ 2]) + im[jj] * swp(im[jj ^ 2]);
      x8 += re[jj] * re[jj ^ 1] + im[jj] * im[jj ^ 1];
      x9 += re[jj].x * re[jj].y + im[jj].x * im[jj].y;
    }
    acc += hw[16] * (x6.x + x6.y);
    acc += hw[17] * (x7.x + x7.y);
    acc += hw[18] * (x8.x + x8.y);
    acc += hw[19] * (2.f * x9);
  }

  // butterfly reduction over the wave (verified primitives)
  acc += partner<32>(acc);
  acc += partner<16>(acc);
  acc += partner<8>(acc);
  acc += partner<4>(acc);
  acc += partner<2>(acc);
  acc += partner<1>(acc);
  if (lane == 0) out[b] = acc + hb[0];
}

extern "C" void kernel_launch(void* const* d_in, const int* in_sizes, int n_in,
                              void* d_out, int out_size, void* d_ws, size_t ws_size,
                              hipStream_t stream) {
  const float* x      = (const float*)d_in[0];
  const float* params = (const float*)d_in[1];
  const float* hw     = (const float*)d_in[2];
  const float* hb     = (const float*)d_in[3];
  float* out = (float*)d_out;
  const int B = in_sizes[0] / 10;
  const int blocks = (B + 3) / 4;  // 4 waves/block, 1 sample/wave
  qreg_kernel<<<blocks, 256, 0, stream>>>(x, params, hw, hb, out, B);
}

// Round 11
// 27.930 us; speedup vs baseline: 2.2325x; 1.0287x over previous
//
#include <hip/hip_runtime.h>

#define DEV __device__ __forceinline__

// One wave (64 lanes) simulates one sample's 1024-amplitude state.
// flat idx = lane*16 + j ; wire w <-> flat bit (9-w):
//   wires 0..5 -> lane bits 5..0 (masks 32,16,8,4,2,1)
//   wires 6..8 -> packed-slot jj bits 2..0 (masks 4,2,1);  wire 9 -> component
// State: f2 re[8], im[8] (packed fp32, v_pk_fma_f32 full-rate).
//
// CNOT chains are never materialized (PHI frame change, verified R10).
// NEW (R11): all wave-uniform trig/matrix building is done ONCE PER BLOCK
// into LDS (threads 0..19: the 20 Rot matrices; threads 64..103: the 4
// samples' encoding sin/cos), then broadcast-read (same-address ds_read
// broadcasts, conflict-free). Removes ~500 redundant VALU instrs/thread.

typedef float f2 __attribute__((ext_vector_type(2)));

DEV float shx(float v, int m) { return __shfl_xor(v, m, 64); }

template <int CTRL>
DEV float dppx(float x) {
  int xi = __builtin_bit_cast(int, x);
  return __builtin_bit_cast(
      float, __builtin_amdgcn_update_dpp(xi, xi, CTRL, 0xF, 0xF, false));
}
template <int OFS>
DEV float swz(float x) {
  return __builtin_bit_cast(
      float, __builtin_amdgcn_ds_swizzle(__builtin_bit_cast(int, x), OFS));
}

template <int M>  // scalar value at lane^M (single-bit masks)
DEV float partner(float x) {
  if constexpr (M == 32) return shx(x, 32);
  else if constexpr (M == 16) return swz<0x401F>(x);
  else if constexpr (M == 8) return dppx<0x128>(x);
  else if constexpr (M == 4) return swz<0x101F>(x);
  else if constexpr (M == 2) return dppx<0x4E>(x);
  else return dppx<0xB1>(x);
}
template <int M>
DEV f2 partner2(f2 v) { return (f2){partner<M>(v.x), partner<M>(v.y)}; }

template <int XM>  // generic lane-xor exchange (multi-bit masks)
DEV float lanex(float x) {
  if constexpr (XM == 48) return shx(x, 48);
  else if constexpr (XM == 40) return shx(x, 40);
  else if constexpr (XM == 24) return swz<0x601F>(x);
  else if constexpr (XM == 20) return swz<0x501F>(x);
  else if constexpr (XM == 12) return swz<0x301F>(x);
  else if constexpr (XM == 10) return swz<0x281F>(x);
  else if constexpr (XM == 6)  return swz<0x181F>(x);
  else if constexpr (XM == 5)  return swz<0x141F>(x);
  else if constexpr (XM == 3)  return swz<0x0C1F>(x);
}
template <int XM>
DEV f2 lanex2(f2 v) { return (f2){lanex<XM>(v.x), lanex<XM>(v.y)}; }

DEV f2 swp(f2 v) { return (f2){v.y, v.x}; }

// ================= layer-1 gates (verified R9) ===============================

template <int M>
DEV void rot_partg(f2 (&re)[8], f2 (&im)[8], int lane,
                   float u00r, float u00i, float u01r, float u01i,
                   float u10r, float u10i, float u11r, float u11i) {
  const bool hi = (lane & M) != 0;
  float Dor = hi ? u11r : u00r, Doi = hi ? u11i : u00i;
  float Dpr = hi ? u10r : u01r, Dpi = hi ? u10i : u01i;
#pragma unroll
  for (int jj = 0; jj < 8; ++jj) {
    f2 pr = partner2<M>(re[jj]), pi = partner2<M>(im[jj]);
    f2 nr = Dor * re[jj] - Doi * im[jj] + Dpr * pr - Dpi * pi;
    f2 ni = Dor * im[jj] + Doi * re[jj] + Dpr * pi + Dpi * pr;
    re[jj] = nr; im[jj] = ni;
  }
}

template <int M2>
DEV void rot_local(f2 (&re)[8], f2 (&im)[8],
                   float u00r, float u00i, float u01r, float u01i,
                   float u10r, float u10i, float u11r, float u11i) {
#pragma unroll
  for (int jj = 0; jj < 8; ++jj) {
    if (jj & M2) continue;
    const int k = jj | M2;
    f2 a0r = re[jj], a0i = im[jj], a1r = re[k], a1i = im[k];
    re[jj] = u00r * a0r - u00i * a0i + u01r * a1r - u01i * a1i;
    im[jj] = u00r * a0i + u00i * a0r + u01r * a1i + u01i * a1r;
    re[k]  = u10r * a0r - u10i * a0i + u11r * a1r - u11i * a1i;
    im[k]  = u10r * a0i + u10i * a0r + u11r * a1i + u11i * a1r;
  }
}

DEV void rot_vec(f2 (&re)[8], f2 (&im)[8],
                 float u00r, float u00i, float u01r, float u01i,
                 float u10r, float u10i, float u11r, float u11i) {
  const f2 Vor = (f2){u00r, u11r}, Voi = (f2){u00i, u11i};
  const f2 Vpr = (f2){u01r, u10r}, Vpi = (f2){u01i, u10i};
#pragma unroll
  for (int jj = 0; jj < 8; ++jj) {
    f2 sr = swp(re[jj]), si = swp(im[jj]);
    f2 nr = Vor * re[jj] - Voi * im[jj] + Vpr * sr - Vpi * si;
    f2 ni = Vor * im[jj] + Voi * re[jj] + Vpr * si + Vpi * sr;
    re[jj] = nr; im[jj] = ni;
  }
}

// ================= layer-2 gates (conjugated by PHI, verified R10) ===========

template <int XM, int SELM>
DEV void rot2_lane(f2 (&re)[8], f2 (&im)[8], int lane,
                   float u00r, float u00i, float u01r, float u01i,
                   float u10r, float u10i, float u11r, float u11i) {
  const bool hi = (__popc(lane & SELM) & 1) != 0;
  float Dor = hi ? u11r : u00r, Doi = hi ? u11i : u00i;
  float Dpr = hi ? u10r : u01r, Dpi = hi ? u10i : u01i;
#pragma unroll
  for (int jj = 0; jj < 8; ++jj) {
    f2 pr = lanex2<XM>(re[jj]), pi = lanex2<XM>(im[jj]);
    f2 nr = Dor * re[jj] - Doi * im[jj] + Dpr * pr - Dpi * pi;
    f2 ni = Dor * im[jj] + Doi * re[jj] + Dpr * pi + Dpi * pr;
    re[jj] = nr; im[jj] = ni;
  }
}

DEV void rot2_w5(f2 (&re)[8], f2 (&im)[8], bool p5,
                 float u00r, float u00i, float u01r, float u01i,
                 float u10r, float u10i, float u11r, float u11i) {
  float Dor = p5 ? u11r : u00r, Doi = p5 ? u11i : u00i;
  float Dpr = p5 ? u10r : u01r, Dpi = p5 ? u10i : u01i;
  f2 o_r[8], o_i[8];
#pragma unroll
  for (int jj = 0; jj < 8; ++jj) { o_r[jj] = re[jj]; o_i[jj] = im[jj]; }
#pragma unroll
  for (int jj = 0; jj < 8; ++jj) {
    const int k = jj ^ 4;
    f2 pr = partner2<1>(o_r[k]), pi = partner2<1>(o_i[k]);
    re[jj] = Dor * o_r[jj] - Doi * o_i[jj] + Dpr * pr - Dpi * pi;
    im[jj] = Dor * o_i[jj] + Doi * o_r[jj] + Dpr * pi + Dpi * pr;
  }
}

template <int M2, int CLS>
DEV void rot2_local(f2 (&re)[8], f2 (&im)[8], bool p5,
                    float u00r, float u00i, float u01r, float u01i,
                    float u10r, float u10i, float u11r, float u11i) {
  const float D0or = p5 ? u11r : u00r, D0oi = p5 ? u11i : u00i;
  const float D0pr = p5 ? u10r : u01r, D0pi = p5 ? u10i : u01i;
  const float D1or = p5 ? u00r : u11r, D1oi = p5 ? u00i : u11i;
  const float D1pr = p5 ? u01r : u10r, D1pi = p5 ? u01i : u10i;
  f2 o_r[8], o_i[8];
#pragma unroll
  for (int jj = 0; jj < 8; ++jj) { o_r[jj] = re[jj]; o_i[jj] = im[jj]; }
#pragma unroll
  for (int jj = 0; jj < 8; ++jj) {
    const int k = jj ^ M2;
    const bool c1 = (__builtin_popcount(jj & CLS) & 1) != 0;
    const float Dor = c1 ? D1or : D0or, Doi = c1 ? D1oi : D0oi;
    const float Dpr = c1 ? D1pr : D0pr, Dpi = c1 ? D1pi : D0pi;
    re[jj] = Dor * o_r[jj] - Doi * o_i[jj] + Dpr * o_r[k] - Dpi * o_i[k];
    im[jj] = Dor * o_i[jj] + Doi * o_r[jj] + Dpr * o_i[k] + Dpi * o_r[k];
  }
}

DEV void rot2_w8(f2 (&re)[8], f2 (&im)[8], bool p5,
                 float u00r, float u00i, float u01r, float u01i,
                 float u10r, float u10i, float u11r, float u11i) {
  const float D0or = p5 ? u11r : u00r, D0oi = p5 ? u11i : u00i;
  const float D0pr = p5 ? u10r : u01r, D0pi = p5 ? u10i : u01i;
  const float D1or = p5 ? u00r : u11r, D1oi = p5 ? u00i : u11i;
  const float D1pr = p5 ? u01r : u10r, D1pi = p5 ? u01i : u10i;
  f2 o_r[8], o_i[8];
#pragma unroll
  for (int jj = 0; jj < 8; ++jj) { o_r[jj] = re[jj]; o_i[jj] = im[jj]; }
#pragma unroll
  for (int jj = 0; jj < 8; ++jj) {
    const int k = jj ^ 1;
    const bool c1 = (__builtin_popcount(jj & 7) & 1) != 0;
    const float Dor = c1 ? D1or : D0or, Doi = c1 ? D1oi : D0oi;
    const float Dpr = c1 ? D1pr : D0pr, Dpi = c1 ? D1pi : D0pi;
    f2 pr = swp(o_r[k]), pi = swp(o_i[k]);
    re[jj] = Dor * o_r[jj] - Doi * o_i[jj] + Dpr * pr - Dpi * pi;
    im[jj] = Dor * o_i[jj] + Doi * o_r[jj] + Dpr * pi + Dpi * pr;
  }
}

DEV void rot2_w9(f2 (&re)[8], f2 (&im)[8], bool p5,
                 float u00r, float u00i, float u01r, float u01i,
                 float u10r, float u10i, float u11r, float u11i) {
  const f2 Vor0 = p5 ? (f2){u11r, u00r} : (f2){u00r, u11r};
  const f2 Voi0 = p5 ? (f2){u11i, u00i} : (f2){u00i, u11i};
  const f2 Vpr0 = p5 ? (f2){u10r, u01r} : (f2){u01r, u10r};
  const f2 Vpi0 = p5 ? (f2){u10i, u01i} : (f2){u01i, u10i};
  const f2 Vor1 = p5 ? (f2){u00r, u11r} : (f2){u11r, u00r};
  const f2 Voi1 = p5 ? (f2){u00i, u11i} : (f2){u11i, u00i};
  const f2 Vpr1 = p5 ? (f2){u01r, u10r} : (f2){u10r, u01r};
  const f2 Vpi1 = p5 ? (f2){u01i, u10i} : (f2){u10i, u01i};
#pragma unroll
  for (int jj = 0; jj < 8; ++jj) {
    const bool c1 = (__builtin_popcount(jj) & 1) != 0;
    const f2 Vor = c1 ? Vor1 : Vor0, Voi = c1 ? Voi1 : Voi0;
    const f2 Vpr = c1 ? Vpr1 : Vpr0, Vpi = c1 ? Vpi1 : Vpi0;
    f2 sr = swp(re[jj]), si = swp(im[jj]);
    f2 nr = Vor * re[jj] - Voi * im[jj] + Vpr * sr - Vpi * si;
    f2 ni = Vor * im[jj] + Voi * re[jj] + Vpr * si + Vpi * sr;
    re[jj] = nr; im[jj] = ni;
  }
}

// ================= U-matrix build (once per block, into LDS) =================

DEV void make_u(const float* __restrict__ pp, float (&u)[8]) {
  // PennyLane Rot = RZ(om) @ RY(th) @ RZ(ph)
  float ph = pp[0], th = pp[1], om = pp[2];
  float s, c;   __sincosf(0.5f * th, &s, &c);
  float sa, ca; __sincosf(0.5f * (ph + om), &sa, &ca);
  float sb, cb; __sincosf(0.5f * (ph - om), &sb, &cb);
  u[0] = c * ca;  u[1] = -c * sa;   // u00
  u[2] = -s * cb; u[3] = -s * sb;   // u01
  u[4] = s * cb;  u[5] = -s * sb;   // u10
  u[6] = c * ca;  u[7] = c * sa;    // u11
}

// ================= dispatch ==================================================

DEV void rot_wire(int w, f2 (&re)[8], f2 (&im)[8], int lane,
                  const float* u) {
  float u00r = u[0], u00i = u[1], u01r = u[2], u01i = u[3];
  float u10r = u[4], u10i = u[5], u11r = u[6], u11i = u[7];
  switch (w) {
    case 0: rot_partg<32>(re, im, lane, u00r, u00i, u01r, u01i, u10r, u10i, u11r, u11i); break;
    case 1: rot_partg<16>(re, im, lane, u00r, u00i, u01r, u01i, u10r, u10i, u11r, u11i); break;
    case 2: rot_partg<8>(re, im, lane, u00r, u00i, u01r, u01i, u10r, u10i, u11r, u11i); break;
    case 3: rot_partg<4>(re, im, lane, u00r, u00i, u01r, u01i, u10r, u10i, u11r, u11i); break;
    case 4: rot_partg<2>(re, im, lane, u00r, u00i, u01r, u01i, u10r, u10i, u11r, u11i); break;
    case 5: rot_partg<1>(re, im, lane, u00r, u00i, u01r, u01i, u10r, u10i, u11r, u11i); break;
    case 6: rot_local<4>(re, im, u00r, u00i, u01r, u01i, u10r, u10i, u11r, u11i); break;
    case 7: rot_local<2>(re, im, u00r, u00i, u01r, u01i, u10r, u10i, u11r, u11i); break;
    case 8: rot_local<1>(re, im, u00r, u00i, u01r, u01i, u10r, u10i, u11r, u11i); break;
    case 9: rot_vec(re, im, u00r, u00i, u01r, u01i, u10r, u10i, u11r, u11i); break;
  }
}

DEV void rot2_wire(int w, f2 (&re)[8], f2 (&im)[8], int lane, bool p5,
                   const float* u) {
  float u00r = u[0], u00i = u[1], u01r = u[2], u01i = u[3];
  float u10r = u[4], u10i = u[5], u11r = u[6], u11i = u[7];
  switch (w) {
    case 0: rot2_lane<48, 32>(re, im, lane, u00r, u00i, u01r, u01i, u10r, u10i, u11r, u11i); break;
    case 1: rot2_lane<24, 48>(re, im, lane, u00r, u00i, u01r, u01i, u10r, u10i, u11r, u11i); break;
    case 2: rot2_lane<12, 56>(re, im, lane, u00r, u00i, u01r, u01i, u10r, u10i, u11r, u11i); break;
    case 3: rot2_lane<6, 60>(re, im, lane, u00r, u00i, u01r, u01i, u10r, u10i, u11r, u11i); break;
    case 4: rot2_lane<3, 62>(re, im, lane, u00r, u00i, u01r, u01i, u10r, u10i, u11r, u11i); break;
    case 5: rot2_w5(re, im, p5, u00r, u00i, u01r, u01i, u10r, u10i, u11r, u11i); break;
    case 6: rot2_local<6, 4>(re, im, p5, u00r, u00i, u01r, u01i, u10r, u10i, u11r, u11i); break;
    case 7: rot2_local<3, 6>(re, im, p5, u00r, u00i, u01r, u01i, u10r, u10i, u11r, u11i); break;
    case 8: rot2_w8(re, im, p5, u00r, u00i, u01r, u01i, u10r, u10i, u11r, u11i); break;
    case 9: rot2_w9(re, im, p5, u00r, u00i, u01r, u01i, u10r, u10i, u11r, u11i); break;
  }
}

// ================= X features (PHI^2 frame, verified R10) ====================

template <int XM>
DEV float xfeat_lane(const f2 (&re)[8], const f2 (&im)[8]) {
  f2 t = (f2){0.f, 0.f};
#pragma unroll
  for (int jj = 0; jj < 8; ++jj)
    t += re[jj] * lanex2<XM>(re[jj]) + im[jj] * lanex2<XM>(im[jj]);
  return t.x + t.y;
}

// ================= kernel ====================================================

__global__ __launch_bounds__(256) void qreg_kernel(
    const float* __restrict__ x,      // (B, 10)
    const float* __restrict__ params, // (60,)
    const float* __restrict__ hw,     // (20,)
    const float* __restrict__ hb,     // (1,)
    float* __restrict__ out,          // (B,)
    int Bn) {
  const int tid = threadIdx.x;
  const int lane = tid & 63;
  const int wv = tid >> 6;
  const int b = blockIdx.x * 4 + wv;
  const bool p5 = (__popc(lane & 63) & 1) != 0;

  // ---- once-per-block wave-uniform precompute (LDS broadcast) ----
  __shared__ __align__(16) float Ulds[20][8];   // 20 Rot matrices
  __shared__ float Enc[4][10][2];               // 4 samples' encoding cos/sin

  if (tid < 20) {
    float u[8];
    make_u(params + tid * 3, u);
#pragma unroll
    for (int k = 0; k < 8; ++k) Ulds[tid][k] = u[k];
  }
  if (tid >= 64 && tid < 104) {
    const int t = tid - 64;
    const int s = t / 10, w = t % 10;
    int bs = blockIdx.x * 4 + s;
    if (bs >= Bn) bs = Bn - 1;
    float sn, cs;
    __sincosf(0.5f * x[bs * 10 + w], &sn, &cs);
    Enc[s][w][0] = cs;
    Enc[s][w][1] = sn;
  }
  __syncthreads();

  f2 re[8], im[8];

  // ---- encoding: RY product state from the LDS trig table ----
  {
    float c_[10], s_[10];
#pragma unroll
    for (int w = 0; w < 10; ++w) { c_[w] = Enc[wv][w][0]; s_[w] = Enc[wv][w][1]; }
    float L = (lane & 32) ? s_[0] : c_[0];
    L *= (lane & 16) ? s_[1] : c_[1];
    L *= (lane & 8) ? s_[2] : c_[2];
    L *= (lane & 4) ? s_[3] : c_[3];
    L *= (lane & 2) ? s_[4] : c_[4];
    L *= (lane & 1) ? s_[5] : c_[5];
    float t2[4], t3[8], t4[16];
    t2[0] = c_[8] * c_[9]; t2[1] = c_[8] * s_[9];
    t2[2] = s_[8] * c_[9]; t2[3] = s_[8] * s_[9];
#pragma unroll
    for (int j = 0; j < 8; ++j) t3[j] = ((j & 4) ? s_[7] : c_[7]) * t2[j & 3];
#pragma unroll
    for (int j = 0; j < 16; ++j) t4[j] = L * ((j & 8) ? s_[6] : c_[6]) * t3[j & 7];
#pragma unroll
    for (int jj = 0; jj < 8; ++jj) {
      re[jj] = (f2){t4[2 * jj], t4[2 * jj + 1]};
      im[jj] = (f2){0.f, 0.f};
    }
  }

  // ---- layer 1: standard Rots (chain handled by frame change) ----
#pragma unroll
  for (int w = 0; w < 10; ++w)
    rot_wire(w, re, im, lane, &Ulds[w][0]);

  // ---- layer 2: Rots conjugated by PHI ----
#pragma unroll
  for (int w = 0; w < 10; ++w)
    rot2_wire(w, re, im, lane, p5, &Ulds[10 + w][0]);

  // ---- features in the PHI^2 frame, folded into head dot-product ----
  f2 Sv = (f2){0.f, 0.f}, t6 = (f2){0.f, 0.f}, t7 = (f2){0.f, 0.f},
     t8 = (f2){0.f, 0.f};
  float t9 = 0.f;
#pragma unroll
  for (int jj = 0; jj < 8; ++jj) {
    f2 pf = re[jj] * re[jj] + im[jj] * im[jj];
    Sv += pf;
    t6 += (jj & 4) ? -pf : pf;
    t7 += (jj & 2) ? -pf : pf;
    t8 += ((__builtin_popcount(jj & 5) & 1)) ? -pf : pf;
    t9 += ((jj & 2) ? -1.f : 1.f) * (pf.x - pf.y);
  }
  const bool pl32 = (lane & 32) != 0, pl16 = (lane & 16) != 0;
  const bool pl40 = (__popc(lane & 40) & 1) != 0;
  const bool pl20 = (__popc(lane & 20) & 1) != 0;
  const bool pl42 = (__popc(lane & 42) & 1) != 0;
  const bool pl21 = (__popc(lane & 21) & 1) != 0;
  const float S_ = Sv.x + Sv.y;
  float acc = 0.f;
  acc += hw[0] * (pl32 ? -S_ : S_);
  acc += hw[1] * (pl16 ? -S_ : S_);
  acc += hw[2] * (pl40 ? -S_ : S_);
  acc += hw[3] * (pl20 ? -S_ : S_);
  acc += hw[4] * (pl42 ? -S_ : S_);
  acc += hw[5] * (pl21 ? -S_ : S_);
  const float t6_ = t6.x + t6.y, t7_ = t7.x + t7.y, t8_ = t8.x + t8.y;
  acc += hw[6] * (pl42 ? -t6_ : t6_);
  acc += hw[7] * (pl21 ? -t7_ : t7_);
  acc += hw[8] * (pl42 ? -t8_ : t8_);
  acc += hw[9] * (pl21 ? -t9 : t9);

  // X_w, wires 0..3: two-bit lane masks 40,20,10,5
  acc += hw[10] * xfeat_lane<40>(re, im);
  acc += hw[11] * xfeat_lane<20>(re, im);
  acc += hw[12] * xfeat_lane<10>(re, im);
  acc += hw[13] * xfeat_lane<5>(re, im);
  // X_4: lane bit1 ^ slot bit2;  X_5: lane bit0 ^ slot bit1
  {
    f2 x4 = (f2){0.f, 0.f}, x5 = (f2){0.f, 0.f};
#pragma unroll
    for (int jj = 0; jj < 8; ++jj) {
      x4 += re[jj] * partner2<2>(re[jj ^ 4]) + im[jj] * partner2<2>(im[jj ^ 4]);
      x5 += re[jj] * partner2<1>(re[jj ^ 2]) + im[jj] * partner2<1>(im[jj ^ 2]);
    }
    acc += hw[14] * (x4.x + x4.y);
    acc += hw[15] * (x5.x + x5.y);
  }
  // X_6: slots jj^5;  X_7: slots jj^2 + comp;  X_8: slots jj^1;  X_9: comp
  {
    f2 x6 = (f2){0.f, 0.f}, x7 = (f2){0.f, 0.f}, x8 = (f2){0.f, 0.f};
    float x9 = 0.f;
#pragma unroll
    for (int jj = 0; jj < 8; ++jj) {
      x6 += re[jj] * re[jj ^ 5] + im[jj] * im[jj ^ 5];
      x7 += re[jj] * swp(re[jj ^ 2]) + im[jj] * swp(im[jj ^ 2]);
      x8 += re[jj] * re[jj ^ 1] + im[jj] * im[jj ^ 1];
      x9 += re[jj].x * re[jj].y + im[jj].x * im[jj].y;
    }
    acc += hw[16] * (x6.x + x6.y);
    acc += hw[17] * (x7.x + x7.y);
    acc += hw[18] * (x8.x + x8.y);
    acc += hw[19] * (2.f * x9);
  }

  // butterfly reduction over the wave (verified primitives)
  acc += partner<32>(acc);
  acc += partner<16>(acc);
  acc += partner<8>(acc);
  acc += partner<4>(acc);
  acc += partner<2>(acc);
  acc += partner<1>(acc);
  if (lane == 0 && b < Bn) out[b] = acc + hb[0];
}

extern "C" void kernel_launch(void* const* d_in, const int* in_sizes, int n_in,
                              void* d_out, int out_size, void* d_ws, size_t ws_size,
                              hipStream_t stream) {
  const float* x      = (const float*)d_in[0];
  const float* params = (const float*)d_in[1];
  const float* hw     = (const float*)d_in[2];
  const float* hb     = (const float*)d_in[3];
  float* out = (float*)d_out;
  const int B = in_sizes[0] / 10;
  const int blocks = (B + 3) / 4;  // 4 waves/block, 1 sample/wave
  qreg_kernel<<<blocks, 256, 0, stream>>>(x, params, hw, hb, out, B);
}

// Round 12
// 27.924 us; speedup vs baseline: 2.2329x; 1.0002x over previous
//
#include <hip/hip_runtime.h>

#define DEV __device__ __forceinline__

// One wave (64 lanes) simulates one sample's 1024-amplitude state.
// flat idx = lane*16 + j ; wire w <-> flat bit (9-w):
//   wires 0..5 -> lane bits 5..0 (masks 32,16,8,4,2,1)
//   wires 6..8 -> packed-slot jj bits 2..0 (masks 4,2,1);  wire 9 -> component
// State: f2 re[8], im[8] (packed fp32, v_pk_fma_f32 full-rate).
//
// CNOT chains are never materialized (PHI frame change, verified R10).
// NEW (R11): all wave-uniform trig/matrix building is done ONCE PER BLOCK
// into LDS (threads 0..19: the 20 Rot matrices; threads 64..103: the 4
// samples' encoding sin/cos), then broadcast-read (same-address ds_read
// broadcasts, conflict-free). Removes ~500 redundant VALU instrs/thread.

typedef float f2 __attribute__((ext_vector_type(2)));

DEV float shx(float v, int m) { return __shfl_xor(v, m, 64); }

template <int CTRL>
DEV float dppx(float x) {
  int xi = __builtin_bit_cast(int, x);
  return __builtin_bit_cast(
      float, __builtin_amdgcn_update_dpp(xi, xi, CTRL, 0xF, 0xF, false));
}
template <int OFS>
DEV float swz(float x) {
  return __builtin_bit_cast(
      float, __builtin_amdgcn_ds_swizzle(__builtin_bit_cast(int, x), OFS));
}

template <int M>  // scalar value at lane^M (single-bit masks)
DEV float partner(float x) {
  if constexpr (M == 32) return shx(x, 32);
  else if constexpr (M == 16) return swz<0x401F>(x);
  else if constexpr (M == 8) return dppx<0x128>(x);
  else if constexpr (M == 4) return swz<0x101F>(x);
  else if constexpr (M == 2) return dppx<0x4E>(x);
  else return dppx<0xB1>(x);
}
template <int M>
DEV f2 partner2(f2 v) { return (f2){partner<M>(v.x), partner<M>(v.y)}; }

template <int XM>  // generic lane-xor exchange (multi-bit masks)
DEV float lanex(float x) {
  if constexpr (XM == 48) return shx(x, 48);
  else if constexpr (XM == 40) return shx(x, 40);
  else if constexpr (XM == 24) return swz<0x601F>(x);
  else if constexpr (XM == 20) return swz<0x501F>(x);
  else if constexpr (XM == 12) return swz<0x301F>(x);
  else if constexpr (XM == 10) return swz<0x281F>(x);
  else if constexpr (XM == 6)  return swz<0x181F>(x);
  else if constexpr (XM == 5)  return swz<0x141F>(x);
  else if constexpr (XM == 3)  return swz<0x0C1F>(x);
}
template <int XM>
DEV f2 lanex2(f2 v) { return (f2){lanex<XM>(v.x), lanex<XM>(v.y)}; }

DEV f2 swp(f2 v) { return (f2){v.y, v.x}; }

// ================= layer-1 gates (verified R9) ===============================

template <int M>
DEV void rot_partg(f2 (&re)[8], f2 (&im)[8], int lane,
                   float u00r, float u00i, float u01r, float u01i,
                   float u10r, float u10i, float u11r, float u11i) {
  const bool hi = (lane & M) != 0;
  float Dor = hi ? u11r : u00r, Doi = hi ? u11i : u00i;
  float Dpr = hi ? u10r : u01r, Dpi = hi ? u10i : u01i;
#pragma unroll
  for (int jj = 0; jj < 8; ++jj) {
    f2 pr = partner2<M>(re[jj]), pi = partner2<M>(im[jj]);
    f2 nr = Dor * re[jj] - Doi * im[jj] + Dpr * pr - Dpi * pi;
    f2 ni = Dor * im[jj] + Doi * re[jj] + Dpr * pi + Dpi * pr;
    re[jj] = nr; im[jj] = ni;
  }
}

template <int M2>
DEV void rot_local(f2 (&re)[8], f2 (&im)[8],
                   float u00r, float u00i, float u01r, float u01i,
                   float u10r, float u10i, float u11r, float u11i) {
#pragma unroll
  for (int jj = 0; jj < 8; ++jj) {
    if (jj & M2) continue;
    const int k = jj | M2;
    f2 a0r = re[jj], a0i = im[jj], a1r = re[k], a1i = im[k];
    re[jj] = u00r * a0r - u00i * a0i + u01r * a1r - u01i * a1i;
    im[jj] = u00r * a0i + u00i * a0r + u01r * a1i + u01i * a1r;
    re[k]  = u10r * a0r - u10i * a0i + u11r * a1r - u11i * a1i;
    im[k]  = u10r * a0i + u10i * a0r + u11r * a1i + u11i * a1r;
  }
}

DEV void rot_vec(f2 (&re)[8], f2 (&im)[8],
                 float u00r, float u00i, float u01r, float u01i,
                 float u10r, float u10i, float u11r, float u11i) {
  const f2 Vor = (f2){u00r, u11r}, Voi = (f2){u00i, u11i};
  const f2 Vpr = (f2){u01r, u10r}, Vpi = (f2){u01i, u10i};
#pragma unroll
  for (int jj = 0; jj < 8; ++jj) {
    f2 sr = swp(re[jj]), si = swp(im[jj]);
    f2 nr = Vor * re[jj] - Voi * im[jj] + Vpr * sr - Vpi * si;
    f2 ni = Vor * im[jj] + Voi * re[jj] + Vpr * si + Vpi * sr;
    re[jj] = nr; im[jj] = ni;
  }
}

// ================= layer-2 gates (conjugated by PHI, verified R10) ===========

template <int XM, int SELM>
DEV void rot2_lane(f2 (&re)[8], f2 (&im)[8], int lane,
                   float u00r, float u00i, float u01r, float u01i,
                   float u10r, float u10i, float u11r, float u11i) {
  const bool hi = (__popc(lane & SELM) & 1) != 0;
  float Dor = hi ? u11r : u00r, Doi = hi ? u11i : u00i;
  float Dpr = hi ? u10r : u01r, Dpi = hi ? u10i : u01i;
#pragma unroll
  for (int jj = 0; jj < 8; ++jj) {
    f2 pr = lanex2<XM>(re[jj]), pi = lanex2<XM>(im[jj]);
    f2 nr = Dor * re[jj] - Doi * im[jj] + Dpr * pr - Dpi * pi;
    f2 ni = Dor * im[jj] + Doi * re[jj] + Dpr * pi + Dpi * pr;
    re[jj] = nr; im[jj] = ni;
  }
}

DEV void rot2_w5(f2 (&re)[8], f2 (&im)[8], bool p5,
                 float u00r, float u00i, float u01r, float u01i,
                 float u10r, float u10i, float u11r, float u11i) {
  float Dor = p5 ? u11r : u00r, Doi = p5 ? u11i : u00i;
  float Dpr = p5 ? u10r : u01r, Dpi = p5 ? u10i : u01i;
  f2 o_r[8], o_i[8];
#pragma unroll
  for (int jj = 0; jj < 8; ++jj) { o_r[jj] = re[jj]; o_i[jj] = im[jj]; }
#pragma unroll
  for (int jj = 0; jj < 8; ++jj) {
    const int k = jj ^ 4;
    f2 pr = partner2<1>(o_r[k]), pi = partner2<1>(o_i[k]);
    re[jj] = Dor * o_r[jj] - Doi * o_i[jj] + Dpr * pr - Dpi * pi;
    im[jj] = Dor * o_i[jj] + Doi * o_r[jj] + Dpr * pi + Dpi * pr;
  }
}

template <int M2, int CLS>
DEV void rot2_local(f2 (&re)[8], f2 (&im)[8], bool p5,
                    float u00r, float u00i, float u01r, float u01i,
                    float u10r, float u10i, float u11r, float u11i) {
  const float D0or = p5 ? u11r : u00r, D0oi = p5 ? u11i : u00i;
  const float D0pr = p5 ? u10r : u01r, D0pi = p5 ? u10i : u01i;
  const float D1or = p5 ? u00r : u11r, D1oi = p5 ? u00i : u11i;
  const float D1pr = p5 ? u01r : u10r, D1pi = p5 ? u01i : u10i;
  f2 o_r[8], o_i[8];
#pragma unroll
  for (int jj = 0; jj < 8; ++jj) { o_r[jj] = re[jj]; o_i[jj] = im[jj]; }
#pragma unroll
  for (int jj = 0; jj < 8; ++jj) {
    const int k = jj ^ M2;
    const bool c1 = (__builtin_popcount(jj & CLS) & 1) != 0;
    const float Dor = c1 ? D1or : D0or, Doi = c1 ? D1oi : D0oi;
    const float Dpr = c1 ? D1pr : D0pr, Dpi = c1 ? D1pi : D0pi;
    re[jj] = Dor * o_r[jj] - Doi * o_i[jj] + Dpr * o_r[k] - Dpi * o_i[k];
    im[jj] = Dor * o_i[jj] + Doi * o_r[jj] + Dpr * o_i[k] + Dpi * o_r[k];
  }
}

DEV void rot2_w8(f2 (&re)[8], f2 (&im)[8], bool p5,
                 float u00r, float u00i, float u01r, float u01i,
                 float u10r, float u10i, float u11r, float u11i) {
  const float D0or = p5 ? u11r : u00r, D0oi = p5 ? u11i : u00i;
  const float D0pr = p5 ? u10r : u01r, D0pi = p5 ? u10i : u01i;
  const float D1or = p5 ? u00r : u11r, D1oi = p5 ? u00i : u11i;
  const float D1pr = p5 ? u01r : u10r, D1pi = p5 ? u01i : u10i;
  f2 o_r[8], o_i[8];
#pragma unroll
  for (int jj = 0; jj < 8; ++jj) { o_r[jj] = re[jj]; o_i[jj] = im[jj]; }
#pragma unroll
  for (int jj = 0; jj < 8; ++jj) {
    const int k = jj ^ 1;
    const bool c1 = (__builtin_popcount(jj & 7) & 1) != 0;
    const float Dor = c1 ? D1or : D0or, Doi = c1 ? D1oi : D0oi;
    const float Dpr = c1 ? D1pr : D0pr, Dpi = c1 ? D1pi : D0pi;
    f2 pr = swp(o_r[k]), pi = swp(o_i[k]);
    re[jj] = Dor * o_r[jj] - Doi * o_i[jj] + Dpr * pr - Dpi * pi;
    im[jj] = Dor * o_i[jj] + Doi * o_r[jj] + Dpr * pi + Dpi * pr;
  }
}

DEV void rot2_w9(f2 (&re)[8], f2 (&im)[8], bool p5,
                 float u00r, float u00i, float u01r, float u01i,
                 float u10r, float u10i, float u11r, float u11i) {
  const f2 Vor0 = p5 ? (f2){u11r, u00r} : (f2){u00r, u11r};
  const f2 Voi0 = p5 ? (f2){u11i, u00i} : (f2){u00i, u11i};
  const f2 Vpr0 = p5 ? (f2){u10r, u01r} : (f2){u01r, u10r};
  const f2 Vpi0 = p5 ? (f2){u10i, u01i} : (f2){u01i, u10i};
  const f2 Vor1 = p5 ? (f2){u00r, u11r} : (f2){u11r, u00r};
  const f2 Voi1 = p5 ? (f2){u00i, u11i} : (f2){u11i, u00i};
  const f2 Vpr1 = p5 ? (f2){u01r, u10r} : (f2){u10r, u01r};
  const f2 Vpi1 = p5 ? (f2){u01i, u10i} : (f2){u10i, u01i};
#pragma unroll
  for (int jj = 0; jj < 8; ++jj) {
    const bool c1 = (__builtin_popcount(jj) & 1) != 0;
    const f2 Vor = c1 ? Vor1 : Vor0, Voi = c1 ? Voi1 : Voi0;
    const f2 Vpr = c1 ? Vpr1 : Vpr0, Vpi = c1 ? Vpi1 : Vpi0;
    f2 sr = swp(re[jj]), si = swp(im[jj]);
    f2 nr = Vor * re[jj] - Voi * im[jj] + Vpr * sr - Vpi * si;
    f2 ni = Vor * im[jj] + Voi * re[jj] + Vpr * si + Vpi * sr;
    re[jj] = nr; im[jj] = ni;
  }
}

// ================= U-matrix build (once per block, into LDS) =================

DEV void make_u(const float* __restrict__ pp, float (&u)[8]) {
  // PennyLane Rot = RZ(om) @ RY(th) @ RZ(ph)
  float ph = pp[0], th = pp[1], om = pp[2];
  float s, c;   __sincosf(0.5f * th, &s, &c);
  float sa, ca; __sincosf(0.5f * (ph + om), &sa, &ca);
  float sb, cb; __sincosf(0.5f * (ph - om), &sb, &cb);
  u[0] = c * ca;  u[1] = -c * sa;   // u00
  u[2] = -s * cb; u[3] = -s * sb;   // u01
  u[4] = s * cb;  u[5] = -s * sb;   // u10
  u[6] = c * ca;  u[7] = c * sa;    // u11
}

// ================= dispatch ==================================================

DEV void rot_wire(int w, f2 (&re)[8], f2 (&im)[8], int lane,
                  const float* u) {
  float u00r = u[0], u00i = u[1], u01r = u[2], u01i = u[3];
  float u10r = u[4], u10i = u[5], u11r = u[6], u11i = u[7];
  switch (w) {
    case 0: rot_partg<32>(re, im, lane, u00r, u00i, u01r, u01i, u10r, u10i, u11r, u11i); break;
    case 1: rot_partg<16>(re, im, lane, u00r, u00i, u01r, u01i, u10r, u10i, u11r, u11i); break;
    case 2: rot_partg<8>(re, im, lane, u00r, u00i, u01r, u01i, u10r, u10i, u11r, u11i); break;
    case 3: rot_partg<4>(re, im, lane, u00r, u00i, u01r, u01i, u10r, u10i, u11r, u11i); break;
    case 4: rot_partg<2>(re, im, lane, u00r, u00i, u01r, u01i, u10r, u10i, u11r, u11i); break;
    case 5: rot_partg<1>(re, im, lane, u00r, u00i, u01r, u01i, u10r, u10i, u11r, u11i); break;
    case 6: rot_local<4>(re, im, u00r, u00i, u01r, u01i, u10r, u10i, u11r, u11i); break;
    case 7: rot_local<2>(re, im, u00r, u00i, u01r, u01i, u10r, u10i, u11r, u11i); break;
    case 8: rot_local<1>(re, im, u00r, u00i, u01r, u01i, u10r, u10i, u11r, u11i); break;
    case 9: rot_vec(re, im, u00r, u00i, u01r, u01i, u10r, u10i, u11r, u11i); break;
  }
}

DEV void rot2_wire(int w, f2 (&re)[8], f2 (&im)[8], int lane, bool p5,
                   const float* u) {
  float u00r = u[0], u00i = u[1], u01r = u[2], u01i = u[3];
  float u10r = u[4], u10i = u[5], u11r = u[6], u11i = u[7];
  switch (w) {
    case 0: rot2_lane<48, 32>(re, im, lane, u00r, u00i, u01r, u01i, u10r, u10i, u11r, u11i); break;
    case 1: rot2_lane<24, 48>(re, im, lane, u00r, u00i, u01r, u01i, u10r, u10i, u11r, u11i); break;
    case 2: rot2_lane<12, 56>(re, im, lane, u00r, u00i, u01r, u01i, u10r, u10i, u11r, u11i); break;
    case 3: rot2_lane<6, 60>(re, im, lane, u00r, u00i, u01r, u01i, u10r, u10i, u11r, u11i); break;
    case 4: rot2_lane<3, 62>(re, im, lane, u00r, u00i, u01r, u01i, u10r, u10i, u11r, u11i); break;
    case 5: rot2_w5(re, im, p5, u00r, u00i, u01r, u01i, u10r, u10i, u11r, u11i); break;
    case 6: rot2_local<6, 4>(re, im, p5, u00r, u00i, u01r, u01i, u10r, u10i, u11r, u11i); break;
    case 7: rot2_local<3, 6>(re, im, p5, u00r, u00i, u01r, u01i, u10r, u10i, u11r, u11i); break;
    case 8: rot2_w8(re, im, p5, u00r, u00i, u01r, u01i, u10r, u10i, u11r, u11i); break;
    case 9: rot2_w9(re, im, p5, u00r, u00i, u01r, u01i, u10r, u10i, u11r, u11i); break;
  }
}

// ================= X features (PHI^2 frame, verified R10) ====================

template <int XM>
DEV float xfeat_lane(const f2 (&re)[8], const f2 (&im)[8]) {
  f2 t = (f2){0.f, 0.f};
#pragma unroll
  for (int jj = 0; jj < 8; ++jj)
    t += re[jj] * lanex2<XM>(re[jj]) + im[jj] * lanex2<XM>(im[jj]);
  return t.x + t.y;
}

// ================= kernel ====================================================

__global__ __launch_bounds__(256) void qreg_kernel(
    const float* __restrict__ x,      // (B, 10)
    const float* __restrict__ params, // (60,)
    const float* __restrict__ hw,     // (20,)
    const float* __restrict__ hb,     // (1,)
    float* __restrict__ out,          // (B,)
    int Bn) {
  const int tid = threadIdx.x;
  const int lane = tid & 63;
  const int wv = tid >> 6;
  const int b = blockIdx.x * 4 + wv;
  const bool p5 = (__popc(lane & 63) & 1) != 0;

  // ---- once-per-block wave-uniform precompute (LDS broadcast) ----
  __shared__ __align__(16) float Ulds[20][8];   // 20 Rot matrices
  __shared__ float Enc[4][10][2];               // 4 samples' encoding cos/sin

  if (tid < 20) {
    float u[8];
    make_u(params + tid * 3, u);
#pragma unroll
    for (int k = 0; k < 8; ++k) Ulds[tid][k] = u[k];
  }
  if (tid >= 64 && tid < 104) {
    const int t = tid - 64;
    const int s = t / 10, w = t % 10;
    int bs = blockIdx.x * 4 + s;
    if (bs >= Bn) bs = Bn - 1;
    float sn, cs;
    __sincosf(0.5f * x[bs * 10 + w], &sn, &cs);
    Enc[s][w][0] = cs;
    Enc[s][w][1] = sn;
  }
  __syncthreads();

  f2 re[8], im[8];

  // ---- encoding: RY product state from the LDS trig table ----
  {
    float c_[10], s_[10];
#pragma unroll
    for (int w = 0; w < 10; ++w) { c_[w] = Enc[wv][w][0]; s_[w] = Enc[wv][w][1]; }
    float L = (lane & 32) ? s_[0] : c_[0];
    L *= (lane & 16) ? s_[1] : c_[1];
    L *= (lane & 8) ? s_[2] : c_[2];
    L *= (lane & 4) ? s_[3] : c_[3];
    L *= (lane & 2) ? s_[4] : c_[4];
    L *= (lane & 1) ? s_[5] : c_[5];
    float t2[4], t3[8], t4[16];
    t2[0] = c_[8] * c_[9]; t2[1] = c_[8] * s_[9];
    t2[2] = s_[8] * c_[9]; t2[3] = s_[8] * s_[9];
#pragma unroll
    for (int j = 0; j < 8; ++j) t3[j] = ((j & 4) ? s_[7] : c_[7]) * t2[j & 3];
#pragma unroll
    for (int j = 0; j < 16; ++j) t4[j] = L * ((j & 8) ? s_[6] : c_[6]) * t3[j & 7];
#pragma unroll
    for (int jj = 0; jj < 8; ++jj) {
      re[jj] = (f2){t4[2 * jj], t4[2 * jj + 1]};
      im[jj] = (f2){0.f, 0.f};
    }
  }

  // ---- layer 1: standard Rots (chain handled by frame change) ----
#pragma unroll
  for (int w = 0; w < 10; ++w)
    rot_wire(w, re, im, lane, &Ulds[w][0]);

  // ---- layer 2: Rots conjugated by PHI ----
#pragma unroll
  for (int w = 0; w < 10; ++w)
    rot2_wire(w, re, im, lane, p5, &Ulds[10 + w][0]);

  // ---- features in the PHI^2 frame, folded into head dot-product ----
  f2 Sv = (f2){0.f, 0.f}, t6 = (f2){0.f, 0.f}, t7 = (f2){0.f, 0.f},
     t8 = (f2){0.f, 0.f};
  float t9 = 0.f;
#pragma unroll
  for (int jj = 0; jj < 8; ++jj) {
    f2 pf = re[jj] * re[jj] + im[jj] * im[jj];
    Sv += pf;
    t6 += (jj & 4) ? -pf : pf;
    t7 += (jj & 2) ? -pf : pf;
    t8 += ((__builtin_popcount(jj & 5) & 1)) ? -pf : pf;
    t9 += ((jj & 2) ? -1.f : 1.f) * (pf.x - pf.y);
  }
  const bool pl32 = (lane & 32) != 0, pl16 = (lane & 16) != 0;
  const bool pl40 = (__popc(lane & 40) & 1) != 0;
  const bool pl20 = (__popc(lane & 20) & 1) != 0;
  const bool pl42 = (__popc(lane & 42) & 1) != 0;
  const bool pl21 = (__popc(lane & 21) & 1) != 0;
  const float S_ = Sv.x + Sv.y;
  float acc = 0.f;
  acc += hw[0] * (pl32 ? -S_ : S_);
  acc += hw[1] * (pl16 ? -S_ : S_);
  acc += hw[2] * (pl40 ? -S_ : S_);
  acc += hw[3] * (pl20 ? -S_ : S_);
  acc += hw[4] * (pl42 ? -S_ : S_);
  acc += hw[5] * (pl21 ? -S_ : S_);
  const float t6_ = t6.x + t6.y, t7_ = t7.x + t7.y, t8_ = t8.x + t8.y;
  acc += hw[6] * (pl42 ? -t6_ : t6_);
  acc += hw[7] * (pl21 ? -t7_ : t7_);
  acc += hw[8] * (pl42 ? -t8_ : t8_);
  acc += hw[9] * (pl21 ? -t9 : t9);

  // X_w, wires 0..3: two-bit lane masks 40,20,10,5
  acc += hw[10] * xfeat_lane<40>(re, im);
  acc += hw[11] * xfeat_lane<20>(re, im);
  acc += hw[12] * xfeat_lane<10>(re, im);
  acc += hw[13] * xfeat_lane<5>(re, im);
  // X_4: lane bit1 ^ slot bit2;  X_5: lane bit0 ^ slot bit1
  {
    f2 x4 = (f2){0.f, 0.f}, x5 = (f2){0.f, 0.f};
#pragma unroll
    for (int jj = 0; jj < 8; ++jj) {
      x4 += re[jj] * partner2<2>(re[jj ^ 4]) + im[jj] * partner2<2>(im[jj ^ 4]);
      x5 += re[jj] * partner2<1>(re[jj ^ 2]) + im[jj] * partner2<1>(im[jj ^ 2]);
    }
    acc += hw[14] * (x4.x + x4.y);
    acc += hw[15] * (x5.x + x5.y);
  }
  // X_6: slots jj^5;  X_7: slots jj^2 + comp;  X_8: slots jj^1;  X_9: comp
  {
    f2 x6 = (f2){0.f, 0.f}, x7 = (f2){0.f, 0.f}, x8 = (f2){0.f, 0.f};
    float x9 = 0.f;
#pragma unroll
    for (int jj = 0; jj < 8; ++jj) {
      x6 += re[jj] * re[jj ^ 5] + im[jj] * im[jj ^ 5];
      x7 += re[jj] * swp(re[jj ^ 2]) + im[jj] * swp(im[jj ^ 2]);
      x8 += re[jj] * re[jj ^ 1] + im[jj] * im[jj ^ 1];
      x9 += re[jj].x * re[jj].y + im[jj].x * im[jj].y;
    }
    acc += hw[16] * (x6.x + x6.y);
    acc += hw[17] * (x7.x + x7.y);
    acc += hw[18] * (x8.x + x8.y);
    acc += hw[19] * (2.f * x9);
  }

  // butterfly reduction over the wave (verified primitives)
  acc += partner<32>(acc);
  acc += partner<16>(acc);
  acc += partner<8>(acc);
  acc += partner<4>(acc);
  acc += partner<2>(acc);
  acc += partner<1>(acc);
  if (lane == 0 && b < Bn) out[b] = acc + hb[0];
}

extern "C" void kernel_launch(void* const* d_in, const int* in_sizes, int n_in,
                              void* d_out, int out_size, void* d_ws, size_t ws_size,
                              hipStream_t stream) {
  const float* x      = (const float*)d_in[0];
  const float* params = (const float*)d_in[1];
  const float* hw     = (const float*)d_in[2];
  const float* hb     = (const float*)d_in[3];
  float* out = (float*)d_out;
  const int B = in_sizes[0] / 10;
  const int blocks = (B + 3) / 4;  // 4 waves/block, 1 sample/wave
  qreg_kernel<<<blocks, 256, 0, stream>>>(x, params, hw, hb, out, B);
}

// Round 13
// 21.335 us; speedup vs baseline: 2.9225x; 1.3088x over previous
//
#include <hip/hip_runtime.h>

#define DEV __device__ __forceinline__

// One wave (64 lanes) simulates one sample's 1024-amplitude state.
// flat idx = lane*16 + j ; wire w <-> flat bit (9-w):
//   wires 0..5 -> lane bits 5..0 (masks 32,16,8,4,2,1)
//   wires 6..8 -> packed-slot jj bits 2..0 (masks 4,2,1);  wire 9 -> component
// State: f2 re[8], im[8] (packed fp32, v_pk_fma_f32 full-rate).
//
// R10: CNOT chains never materialized (PHI frame change).
// R11: wave-uniform trig/matrix building once per block into LDS.
// NEW (R13): layer-1 Rots are folded into the encoding product state.
// After encoding, the state is a product state; layer-1 single-qubit gates
// keep it a product state with complex factors g_w = U_w @ (cos,sin)^T.
// Each thread builds amp = prod_w g_w(bit_w) directly (~120 instrs),
// replacing the 10-gate chain (~900 instrs, 48 cross-lane exchanges).

typedef float f2 __attribute__((ext_vector_type(2)));

DEV float shx(float v, int m) { return __shfl_xor(v, m, 64); }

template <int CTRL>
DEV float dppx(float x) {
  int xi = __builtin_bit_cast(int, x);
  return __builtin_bit_cast(
      float, __builtin_amdgcn_update_dpp(xi, xi, CTRL, 0xF, 0xF, false));
}
template <int OFS>
DEV float swz(float x) {
  return __builtin_bit_cast(
      float, __builtin_amdgcn_ds_swizzle(__builtin_bit_cast(int, x), OFS));
}

template <int M>  // scalar value at lane^M (single-bit masks)
DEV float partner(float x) {
  if constexpr (M == 32) return shx(x, 32);
  else if constexpr (M == 16) return swz<0x401F>(x);
  else if constexpr (M == 8) return dppx<0x128>(x);
  else if constexpr (M == 4) return swz<0x101F>(x);
  else if constexpr (M == 2) return dppx<0x4E>(x);
  else return dppx<0xB1>(x);
}
template <int M>
DEV f2 partner2(f2 v) { return (f2){partner<M>(v.x), partner<M>(v.y)}; }

template <int XM>  // generic lane-xor exchange (multi-bit masks)
DEV float lanex(float x) {
  if constexpr (XM == 48) return shx(x, 48);
  else if constexpr (XM == 40) return shx(x, 40);
  else if constexpr (XM == 24) return swz<0x601F>(x);
  else if constexpr (XM == 20) return swz<0x501F>(x);
  else if constexpr (XM == 12) return swz<0x301F>(x);
  else if constexpr (XM == 10) return swz<0x281F>(x);
  else if constexpr (XM == 6)  return swz<0x181F>(x);
  else if constexpr (XM == 5)  return swz<0x141F>(x);
  else if constexpr (XM == 3)  return swz<0x0C1F>(x);
}
template <int XM>
DEV f2 lanex2(f2 v) { return (f2){lanex<XM>(v.x), lanex<XM>(v.y)}; }

DEV f2 swp(f2 v) { return (f2){v.y, v.x}; }

// ================= layer-2 gates (conjugated by PHI, verified R10/R12) =======

template <int XM, int SELM>
DEV void rot2_lane(f2 (&re)[8], f2 (&im)[8], int lane,
                   float u00r, float u00i, float u01r, float u01i,
                   float u10r, float u10i, float u11r, float u11i) {
  const bool hi = (__popc(lane & SELM) & 1) != 0;
  float Dor = hi ? u11r : u00r, Doi = hi ? u11i : u00i;
  float Dpr = hi ? u10r : u01r, Dpi = hi ? u10i : u01i;
#pragma unroll
  for (int jj = 0; jj < 8; ++jj) {
    f2 pr = lanex2<XM>(re[jj]), pi = lanex2<XM>(im[jj]);
    f2 nr = Dor * re[jj] - Doi * im[jj] + Dpr * pr - Dpi * pi;
    f2 ni = Dor * im[jj] + Doi * re[jj] + Dpr * pi + Dpi * pr;
    re[jj] = nr; im[jj] = ni;
  }
}

DEV void rot2_w5(f2 (&re)[8], f2 (&im)[8], bool p5,
                 float u00r, float u00i, float u01r, float u01i,
                 float u10r, float u10i, float u11r, float u11i) {
  float Dor = p5 ? u11r : u00r, Doi = p5 ? u11i : u00i;
  float Dpr = p5 ? u10r : u01r, Dpi = p5 ? u10i : u01i;
  f2 o_r[8], o_i[8];
#pragma unroll
  for (int jj = 0; jj < 8; ++jj) { o_r[jj] = re[jj]; o_i[jj] = im[jj]; }
#pragma unroll
  for (int jj = 0; jj < 8; ++jj) {
    const int k = jj ^ 4;
    f2 pr = partner2<1>(o_r[k]), pi = partner2<1>(o_i[k]);
    re[jj] = Dor * o_r[jj] - Doi * o_i[jj] + Dpr * pr - Dpi * pi;
    im[jj] = Dor * o_i[jj] + Doi * o_r[jj] + Dpr * pi + Dpi * pr;
  }
}

template <int M2, int CLS>
DEV void rot2_local(f2 (&re)[8], f2 (&im)[8], bool p5,
                    float u00r, float u00i, float u01r, float u01i,
                    float u10r, float u10i, float u11r, float u11i) {
  const float D0or = p5 ? u11r : u00r, D0oi = p5 ? u11i : u00i;
  const float D0pr = p5 ? u10r : u01r, D0pi = p5 ? u10i : u01i;
  const float D1or = p5 ? u00r : u11r, D1oi = p5 ? u00i : u11i;
  const float D1pr = p5 ? u01r : u10r, D1pi = p5 ? u01i : u10i;
  f2 o_r[8], o_i[8];
#pragma unroll
  for (int jj = 0; jj < 8; ++jj) { o_r[jj] = re[jj]; o_i[jj] = im[jj]; }
#pragma unroll
  for (int jj = 0; jj < 8; ++jj) {
    const int k = jj ^ M2;
    const bool c1 = (__builtin_popcount(jj & CLS) & 1) != 0;
    const float Dor = c1 ? D1or : D0or, Doi = c1 ? D1oi : D0oi;
    const float Dpr = c1 ? D1pr : D0pr, Dpi = c1 ? D1pi : D0pi;
    re[jj] = Dor * o_r[jj] - Doi * o_i[jj] + Dpr * o_r[k] - Dpi * o_i[k];
    im[jj] = Dor * o_i[jj] + Doi * o_r[jj] + Dpr * o_i[k] + Dpi * o_r[k];
  }
}

DEV void rot2_w8(f2 (&re)[8], f2 (&im)[8], bool p5,
                 float u00r, float u00i, float u01r, float u01i,
                 float u10r, float u10i, float u11r, float u11i) {
  const float D0or = p5 ? u11r : u00r, D0oi = p5 ? u11i : u00i;
  const float D0pr = p5 ? u10r : u01r, D0pi = p5 ? u10i : u01i;
  const float D1or = p5 ? u00r : u11r, D1oi = p5 ? u00i : u11i;
  const float D1pr = p5 ? u01r : u10r, D1pi = p5 ? u01i : u10i;
  f2 o_r[8], o_i[8];
#pragma unroll
  for (int jj = 0; jj < 8; ++jj) { o_r[jj] = re[jj]; o_i[jj] = im[jj]; }
#pragma unroll
  for (int jj = 0; jj < 8; ++jj) {
    const int k = jj ^ 1;
    const bool c1 = (__builtin_popcount(jj & 7) & 1) != 0;
    const float Dor = c1 ? D1or : D0or, Doi = c1 ? D1oi : D0oi;
    const float Dpr = c1 ? D1pr : D0pr, Dpi = c1 ? D1pi : D0pi;
    f2 pr = swp(o_r[k]), pi = swp(o_i[k]);
    re[jj] = Dor * o_r[jj] - Doi * o_i[jj] + Dpr * pr - Dpi * pi;
    im[jj] = Dor * o_i[jj] + Doi * o_r[jj] + Dpr * pi + Dpi * pr;
  }
}

DEV void rot2_w9(f2 (&re)[8], f2 (&im)[8], bool p5,
                 float u00r, float u00i, float u01r, float u01i,
                 float u10r, float u10i, float u11r, float u11i) {
  const f2 Vor0 = p5 ? (f2){u11r, u00r} : (f2){u00r, u11r};
  const f2 Voi0 = p5 ? (f2){u11i, u00i} : (f2){u00i, u11i};
  const f2 Vpr0 = p5 ? (f2){u10r, u01r} : (f2){u01r, u10r};
  const f2 Vpi0 = p5 ? (f2){u10i, u01i} : (f2){u01i, u10i};
  const f2 Vor1 = p5 ? (f2){u00r, u11r} : (f2){u11r, u00r};
  const f2 Voi1 = p5 ? (f2){u00i, u11i} : (f2){u11i, u00i};
  const f2 Vpr1 = p5 ? (f2){u01r, u10r} : (f2){u10r, u01r};
  const f2 Vpi1 = p5 ? (f2){u01i, u10i} : (f2){u10i, u01i};
#pragma unroll
  for (int jj = 0; jj < 8; ++jj) {
    const bool c1 = (__builtin_popcount(jj) & 1) != 0;
    const f2 Vor = c1 ? Vor1 : Vor0, Voi = c1 ? Voi1 : Voi0;
    const f2 Vpr = c1 ? Vpr1 : Vpr0, Vpi = c1 ? Vpi1 : Vpi0;
    f2 sr = swp(re[jj]), si = swp(im[jj]);
    f2 nr = Vor * re[jj] - Voi * im[jj] + Vpr * sr - Vpi * si;
    f2 ni = Vor * im[jj] + Voi * re[jj] + Vpr * si + Vpi * sr;
    re[jj] = nr; im[jj] = ni;
  }
}

// ================= U-matrix build =============================================

DEV void make_u(const float* __restrict__ pp, float (&u)[8]) {
  // PennyLane Rot = RZ(om) @ RY(th) @ RZ(ph)
  float ph = pp[0], th = pp[1], om = pp[2];
  float s, c;   __sincosf(0.5f * th, &s, &c);
  float sa, ca; __sincosf(0.5f * (ph + om), &sa, &ca);
  float sb, cb; __sincosf(0.5f * (ph - om), &sb, &cb);
  u[0] = c * ca;  u[1] = -c * sa;   // u00
  u[2] = -s * cb; u[3] = -s * sb;   // u01
  u[4] = s * cb;  u[5] = -s * sb;   // u10
  u[6] = c * ca;  u[7] = c * sa;    // u11
}

DEV void rot2_wire(int w, f2 (&re)[8], f2 (&im)[8], int lane, bool p5,
                   const float* u) {
  float u00r = u[0], u00i = u[1], u01r = u[2], u01i = u[3];
  float u10r = u[4], u10i = u[5], u11r = u[6], u11i = u[7];
  switch (w) {
    case 0: rot2_lane<48, 32>(re, im, lane, u00r, u00i, u01r, u01i, u10r, u10i, u11r, u11i); break;
    case 1: rot2_lane<24, 48>(re, im, lane, u00r, u00i, u01r, u01i, u10r, u10i, u11r, u11i); break;
    case 2: rot2_lane<12, 56>(re, im, lane, u00r, u00i, u01r, u01i, u10r, u10i, u11r, u11i); break;
    case 3: rot2_lane<6, 60>(re, im, lane, u00r, u00i, u01r, u01i, u10r, u10i, u11r, u11i); break;
    case 4: rot2_lane<3, 62>(re, im, lane, u00r, u00i, u01r, u01i, u10r, u10i, u11r, u11i); break;
    case 5: rot2_w5(re, im, p5, u00r, u00i, u01r, u01i, u10r, u10i, u11r, u11i); break;
    case 6: rot2_local<6, 4>(re, im, p5, u00r, u00i, u01r, u01i, u10r, u10i, u11r, u11i); break;
    case 7: rot2_local<3, 6>(re, im, p5, u00r, u00i, u01r, u01i, u10r, u10i, u11r, u11i); break;
    case 8: rot2_w8(re, im, p5, u00r, u00i, u01r, u01i, u10r, u10i, u11r, u11i); break;
    case 9: rot2_w9(re, im, p5, u00r, u00i, u01r, u01i, u10r, u10i, u11r, u11i); break;
  }
}

// ================= X features (PHI^2 frame, verified R10/R12) ================

template <int XM>
DEV float xfeat_lane(const f2 (&re)[8], const f2 (&im)[8]) {
  f2 t = (f2){0.f, 0.f};
#pragma unroll
  for (int jj = 0; jj < 8; ++jj)
    t += re[jj] * lanex2<XM>(re[jj]) + im[jj] * lanex2<XM>(im[jj]);
  return t.x + t.y;
}

// ================= kernel ====================================================

__global__ __launch_bounds__(256) void qreg_kernel(
    const float* __restrict__ x,      // (B, 10)
    const float* __restrict__ params, // (60,)
    const float* __restrict__ hw,     // (20,)
    const float* __restrict__ hb,     // (1,)
    float* __restrict__ out,          // (B,)
    int Bn) {
  const int tid = threadIdx.x;
  const int lane = tid & 63;
  const int wv = tid >> 6;
  const int b = blockIdx.x * 4 + wv;
  const bool p5 = (__popc(lane & 63) & 1) != 0;

  // ---- once-per-block precompute (LDS broadcast) ----
  __shared__ __align__(16) float Ulds[10][8];   // layer-2 Rot matrices
  __shared__ __align__(16) float Enc[4][10][4]; // per-sample g_w = U_w1 @ (c,s)

  if (tid < 10) {
    float u[8];
    make_u(params + (10 + tid) * 3, u);
#pragma unroll
    for (int k = 0; k < 8; ++k) Ulds[tid][k] = u[k];
  }
  if (tid >= 64 && tid < 104) {
    const int t = tid - 64;
    const int s = t / 10, w = t % 10;
    int bs = blockIdx.x * 4 + s;
    if (bs >= Bn) bs = Bn - 1;
    float sn, cs;
    __sincosf(0.5f * x[bs * 10 + w], &sn, &cs);
    float u[8];
    make_u(params + w * 3, u);  // layer-1 U for this wire
    // g = U @ (cs, sn)^T  (cs,sn real)
    Enc[s][w][0] = u[0] * cs + u[2] * sn;  // g0r
    Enc[s][w][1] = u[1] * cs + u[3] * sn;  // g0i
    Enc[s][w][2] = u[4] * cs + u[6] * sn;  // g1r
    Enc[s][w][3] = u[5] * cs + u[7] * sn;  // g1i
  }
  __syncthreads();

  f2 re[8], im[8];

  // ---- product state = encoding ⊗ layer-1 (complex factors) ----
  {
    float g0r[10], g0i[10], g1r[10], g1i[10];
#pragma unroll
    for (int w = 0; w < 10; ++w) {
      g0r[w] = Enc[wv][w][0]; g0i[w] = Enc[wv][w][1];
      g1r[w] = Enc[wv][w][2]; g1i[w] = Enc[wv][w][3];
    }
    // lane factor L (complex): wires 0..5 <-> lane bits 5..0
    float Lr = (lane & 32) ? g1r[0] : g0r[0];
    float Li = (lane & 32) ? g1i[0] : g0i[0];
#pragma unroll
    for (int w = 1; w < 6; ++w) {
      const int m = 1 << (5 - w);
      float ar = (lane & m) ? g1r[w] : g0r[w];
      float ai = (lane & m) ? g1i[w] : g0i[w];
      float nr = Lr * ar - Li * ai;
      float ni = Lr * ai + Li * ar;
      Lr = nr; Li = ni;
    }
    // m6[b6] = L * g6[b6]
    float m6r[2], m6i[2];
#pragma unroll
    for (int bq = 0; bq < 2; ++bq) {
      float ar = bq ? g1r[6] : g0r[6], ai = bq ? g1i[6] : g0i[6];
      m6r[bq] = Lr * ar - Li * ai;
      m6i[bq] = Lr * ai + Li * ar;
    }
    // m67[b6*2+b7] = m6[b6] * g7[b7]
    float m67r[4], m67i[4];
#pragma unroll
    for (int q = 0; q < 4; ++q) {
      const int b6 = q >> 1, b7 = q & 1;
      float ar = b7 ? g1r[7] : g0r[7], ai = b7 ? g1i[7] : g0i[7];
      m67r[q] = m6r[b6] * ar - m6i[b6] * ai;
      m67i[q] = m6r[b6] * ai + m6i[b6] * ar;
    }
    // P[jj] = m67[jj>>1] * g8[jj&1]   (jj bits: b6 b7 b8)
    // amp[jj] = P[jj] * g9(component pair)
    const f2 g9r = (f2){g0r[9], g1r[9]}, g9i = (f2){g0i[9], g1i[9]};
#pragma unroll
    for (int jj = 0; jj < 8; ++jj) {
      const int q = jj >> 1, b8 = jj & 1;
      float ar = b8 ? g1r[8] : g0r[8], ai = b8 ? g1i[8] : g0i[8];
      float Pr = m67r[q] * ar - m67i[q] * ai;
      float Pi = m67r[q] * ai + m67i[q] * ar;
      re[jj] = Pr * g9r - Pi * g9i;
      im[jj] = Pr * g9i + Pi * g9r;
    }
  }

  // ---- layer 2: Rots conjugated by PHI ----
#pragma unroll
  for (int w = 0; w < 10; ++w)
    rot2_wire(w, re, im, lane, p5, &Ulds[w][0]);

  // ---- features in the PHI^2 frame, folded into head dot-product ----
  f2 Sv = (f2){0.f, 0.f}, t6 = (f2){0.f, 0.f}, t7 = (f2){0.f, 0.f},
     t8 = (f2){0.f, 0.f};
  float t9 = 0.f;
#pragma unroll
  for (int jj = 0; jj < 8; ++jj) {
    f2 pf = re[jj] * re[jj] + im[jj] * im[jj];
    Sv += pf;
    t6 += (jj & 4) ? -pf : pf;
    t7 += (jj & 2) ? -pf : pf;
    t8 += ((__builtin_popcount(jj & 5) & 1)) ? -pf : pf;
    t9 += ((jj & 2) ? -1.f : 1.f) * (pf.x - pf.y);
  }
  const bool pl32 = (lane & 32) != 0, pl16 = (lane & 16) != 0;
  const bool pl40 = (__popc(lane & 40) & 1) != 0;
  const bool pl20 = (__popc(lane & 20) & 1) != 0;
  const bool pl42 = (__popc(lane & 42) & 1) != 0;
  const bool pl21 = (__popc(lane & 21) & 1) != 0;
  const float S_ = Sv.x + Sv.y;
  float acc = 0.f;
  acc += hw[0] * (pl32 ? -S_ : S_);
  acc += hw[1] * (pl16 ? -S_ : S_);
  acc += hw[2] * (pl40 ? -S_ : S_);
  acc += hw[3] * (pl20 ? -S_ : S_);
  acc += hw[4] * (pl42 ? -S_ : S_);
  acc += hw[5] * (pl21 ? -S_ : S_);
  const float t6_ = t6.x + t6.y, t7_ = t7.x + t7.y, t8_ = t8.x + t8.y;
  acc += hw[6] * (pl42 ? -t6_ : t6_);
  acc += hw[7] * (pl21 ? -t7_ : t7_);
  acc += hw[8] * (pl42 ? -t8_ : t8_);
  acc += hw[9] * (pl21 ? -t9 : t9);

  // X_w, wires 0..3: two-bit lane masks 40,20,10,5
  acc += hw[10] * xfeat_lane<40>(re, im);
  acc += hw[11] * xfeat_lane<20>(re, im);
  acc += hw[12] * xfeat_lane<10>(re, im);
  acc += hw[13] * xfeat_lane<5>(re, im);
  // X_4: lane bit1 ^ slot bit2;  X_5: lane bit0 ^ slot bit1
  {
    f2 x4 = (f2){0.f, 0.f}, x5 = (f2){0.f, 0.f};
#pragma unroll
    for (int jj = 0; jj < 8; ++jj) {
      x4 += re[jj] * partner2<2>(re[jj ^ 4]) + im[jj] * partner2<2>(im[jj ^ 4]);
      x5 += re[jj] * partner2<1>(re[jj ^ 2]) + im[jj] * partner2<1>(im[jj ^ 2]);
    }
    acc += hw[14] * (x4.x + x4.y);
    acc += hw[15] * (x5.x + x5.y);
  }
  // X_6: slots jj^5;  X_7: slots jj^2 + comp;  X_8: slots jj^1;  X_9: comp
  {
    f2 x6 = (f2){0.f, 0.f}, x7 = (f2){0.f, 0.f}, x8 = (f2){0.f, 0.f};
    float x9 = 0.f;
#pragma unroll
    for (int jj = 0; jj < 8; ++jj) {
      x6 += re[jj] * re[jj ^ 5] + im[jj] * im[jj ^ 5];
      x7 += re[jj] * swp(re[jj ^ 2]) + im[jj] * swp(im[jj ^ 2]);
      x8 += re[jj] * re[jj ^ 1] + im[jj] * im[jj ^ 1];
      x9 += re[jj].x * re[jj].y + im[jj].x * im[jj].y;
    }
    acc += hw[16] * (x6.x + x6.y);
    acc += hw[17] * (x7.x + x7.y);
    acc += hw[18] * (x8.x + x8.y);
    acc += hw[19] * (2.f * x9);
  }

  // butterfly reduction over the wave (verified primitives)
  acc += partner<32>(acc);
  acc += partner<16>(acc);
  acc += partner<8>(acc);
  acc += partner<4>(acc);
  acc += partner<2>(acc);
  acc += partner<1>(acc);
  if (lane == 0 && b < Bn) out[b] = acc + hb[0];
}

extern "C" void kernel_launch(void* const* d_in, const int* in_sizes, int n_in,
                              void* d_out, int out_size, void* d_ws, size_t ws_size,
                              hipStream_t stream) {
  const float* x      = (const float*)d_in[0];
  const float* params = (const float*)d_in[1];
  const float* hw     = (const float*)d_in[2];
  const float* hb     = (const float*)d_in[3];
  float* out = (float*)d_out;
  const int B = in_sizes[0] / 10;
  const int blocks = (B + 3) / 4;  // 4 waves/block, 1 sample/wave
  qreg_kernel<<<blocks, 256, 0, stream>>>(x, params, hw, hb, out, B);
}